// Round 1
// baseline (431.390 us; speedup 1.0000x reference)
//
#include <hip/hip_runtime.h>
#include <hip/hip_bf16.h>

#define M_TOTAL 65536
#define DIM 768
#define KC 64
#define INV_T 10.0f

typedef __attribute__((ext_vector_type(4))) float f32x4;
typedef __attribute__((ext_vector_type(8))) short bf16x8;

__device__ __forceinline__ short f2bf(float f) {
    union { float f; unsigned u; } x; x.f = f;
    unsigned u = x.u;
    unsigned r = (u + 0x7fffu + ((u >> 16) & 1u)) >> 16;
    return (short)r;
}

// ---------------- K0: normalize centers -> cn (fp32) + cnbf (bf16) ----------------
__global__ __launch_bounds__(256) void k_centers(const float* __restrict__ centers,
                                                 float* __restrict__ cn,
                                                 short* __restrict__ cnbf) {
    int k = blockIdx.x, tid = threadIdx.x;
    float ss = 0.f;
    for (int i = tid; i < DIM; i += 256) { float v = centers[k * DIM + i]; ss += v * v; }
    __shared__ float red[4];
    for (int o = 32; o; o >>= 1) ss += __shfl_xor(ss, o);
    if ((tid & 63) == 0) red[tid >> 6] = ss;
    __syncthreads();
    ss = red[0] + red[1] + red[2] + red[3];
    float inv = 1.0f / fmaxf(sqrtf(ss), 1e-12f);
    for (int i = tid; i < DIM; i += 256) {
        float v = centers[k * DIM + i] * inv;
        cn[k * DIM + i] = v;
        cnbf[k * DIM + i] = f2bf(v);
    }
}

// ---------------- K1: logits GEMM (bf16 MFMA) + exp -> E, invnorm, col sums -------
// Each wave: 16 rows x all 64 clusters. A-frag from global fp32 (cvt to bf16),
// B-frag from L2-resident cnbf. Row-normalization folded into epilogue scale.
__global__ __launch_bounds__(256) void k_logits(const float* __restrict__ F,
                                                const short* __restrict__ cnbf,
                                                float* __restrict__ E,
                                                float* __restrict__ invn,
                                                float* __restrict__ sr0) {
    int tid = threadIdx.x;
    int wave = tid >> 6, lane = tid & 63;
    int l15 = lane & 15, lhi = lane >> 4;
    int rowbase = blockIdx.x * 64 + wave * 16;

    const float* Arow = F + (size_t)(rowbase + l15) * DIM + lhi * 8;
    const short* Bbase = cnbf + (size_t)l15 * DIM + lhi * 8;

    f32x4 acc[4];
#pragma unroll
    for (int n = 0; n < 4; ++n) acc[n] = (f32x4){0.f, 0.f, 0.f, 0.f};
    float ss = 0.f;

#pragma unroll
    for (int kb = 0; kb < DIM; kb += 32) {
        float4 a0 = *(const float4*)(Arow + kb);
        float4 a1 = *(const float4*)(Arow + kb + 4);
        ss += a0.x * a0.x + a0.y * a0.y + a0.z * a0.z + a0.w * a0.w;
        ss += a1.x * a1.x + a1.y * a1.y + a1.z * a1.z + a1.w * a1.w;
        bf16x8 af;
        af[0] = f2bf(a0.x); af[1] = f2bf(a0.y); af[2] = f2bf(a0.z); af[3] = f2bf(a0.w);
        af[4] = f2bf(a1.x); af[5] = f2bf(a1.y); af[6] = f2bf(a1.z); af[7] = f2bf(a1.w);
#pragma unroll
        for (int n = 0; n < 4; ++n) {
            bf16x8 b = *(const bf16x8*)(Bbase + (size_t)n * 16 * DIM + kb);
            acc[n] = __builtin_amdgcn_mfma_f32_16x16x32_bf16(af, b, acc[n], 0, 0, 0);
        }
    }

    // per-row sumsq: lane covered row l15; reduce over the 4 lhi groups
    ss += __shfl_xor(ss, 16);
    ss += __shfl_xor(ss, 32);
    float inv = 1.0f / fmaxf(sqrtf(ss), 1e-12f);
    if (lane < 16) invn[rowbase + lane] = inv;

    // D-frag rows are (lhi*4 + j); fetch their invnorms (held by lanes 0..15)
    float sc[4];
#pragma unroll
    for (int j = 0; j < 4; ++j) sc[j] = __shfl(inv, lhi * 4 + j) * INV_T;

    float colp[4] = {0.f, 0.f, 0.f, 0.f};
#pragma unroll
    for (int n = 0; n < 4; ++n) {
#pragma unroll
        for (int j = 0; j < 4; ++j) {
            float e = expf(acc[n][j] * sc[j]);
            E[(size_t)(rowbase + lhi * 4 + j) * KC + n * 16 + l15] = e;
            colp[n] += e;
        }
    }
#pragma unroll
    for (int n = 0; n < 4; ++n) {
        colp[n] += __shfl_xor(colp[n], 16);
        colp[n] += __shfl_xor(colp[n], 32);
    }
    __shared__ float bsr[KC];
    if (tid < KC) bsr[tid] = 0.f;
    __syncthreads();
    if (lane < 16) {
#pragma unroll
        for (int n = 0; n < 4; ++n) atomicAdd(&bsr[n * 16 + lane], colp[n]);
    }
    __syncthreads();
    if (tid < KC) atomicAdd(&sr0[tid], bsr[tid]);
}

// ---------------- T kernels: per-cluster scale updates (1 wave) -------------------
__global__ void k_t1(const float* __restrict__ sr0, float* __restrict__ R) {
    int t = threadIdx.x;
    float s0 = sr0[t];
    float tot = s0;
    for (int o = 32; o; o >>= 1) tot += __shfl_xor(tot, o);
    float S = fmaxf(tot, 1e-12f);
    R[t] = (1.0f / S) / (fmaxf(s0 / S, 1e-12f) * 64.0f);
}

__global__ void k_t23(const float* __restrict__ srX, float* __restrict__ R) {
    int t = threadIdx.x;
    float r = R[t];
    R[t] = r / (fmaxf(r * srX[t], 1e-12f) * 64.0f);
}

// ---------------- P: fused col-step + next row-step accumulation ------------------
// MODE 0: c_old = 1 (first col step), writes c, accumulates srNext
// MODE 1: reads/writes c, accumulates srNext
// MODE 2: final col step -> writes assignments + mass
template <int MODE>
__global__ __launch_bounds__(256) void k_sink(const float* __restrict__ E,
                                              const float* __restrict__ R,
                                              float* __restrict__ c,
                                              float* __restrict__ srNext,
                                              float* __restrict__ Aout,
                                              float* __restrict__ mass) {
    int tid = threadIdx.x, lane = tid & 63;
    int gw = blockIdx.x * 4 + (tid >> 6);
    float Rl = R[lane];
    float wacc = 0.f;
    int m0 = gw * 16;
    for (int i = 0; i < 16; ++i) {
        int m = m0 + i;
        float e = E[(size_t)m * KC + lane];
        float v = e * Rl;
        float s = v;
        for (int o = 32; o; o >>= 1) s += __shfl_xor(s, o);
        float cold = (MODE == 0) ? 1.0f : c[m];
        float cs = cold * s;
        float cnew = cold / (fmaxf(cs, 1e-12f) * 65536.0f);
        if (MODE == 2) {
            float a = v * cnew * 65536.0f;
            Aout[(size_t)m * KC + lane] = a;
            wacc += a;
        } else {
            if (lane == 0) c[m] = cnew;
            wacc += e * cnew;
        }
    }
    __shared__ float bacc[KC];
    if (tid < KC) bacc[tid] = 0.f;
    __syncthreads();
    atomicAdd(&bacc[lane], wacc);
    __syncthreads();
    if (tid < KC) atomicAdd((MODE == 2 ? mass : srNext) + tid, bacc[tid]);
}

// ---------------- K3: weighted centers, fp32 outer-product ------------------------
// weighted[k][dd] = sum_m (A[m][k]*invn[m]) * F[m][dd].  Block: 256 m-rows, 768 thr
// (thread = one dd column, 64 k-accumulators). A*inv staged in LDS (broadcast reads).
__global__ __launch_bounds__(768) void k_weighted(const float* __restrict__ F,
                                                  const float* __restrict__ A,
                                                  const float* __restrict__ invn,
                                                  float* __restrict__ outP,
                                                  int twoStage) {
    __shared__ float asld[256 * KC];  // 64 KiB
    int tid = threadIdx.x;
    int mb = blockIdx.x * 256;
    for (int idx = tid; idx < 256 * KC; idx += 768) {
        int mi = idx >> 6, k = idx & 63;
        asld[idx] = A[(size_t)(mb + mi) * KC + k] * invn[mb + mi];
    }
    __syncthreads();

    int dd = tid;
    float acc[KC];
#pragma unroll
    for (int k = 0; k < KC; ++k) acc[k] = 0.f;

    const float* Fp = F + (size_t)mb * DIM + dd;
    float tb[4];
#pragma unroll
    for (int j = 0; j < 4; ++j) tb[j] = Fp[(size_t)j * DIM];

    for (int mi = 0; mi < 256; mi += 4) {
        int mn = (mi + 4 < 256) ? (mi + 4) : mi;  // clamped prefetch (redundant at tail)
        float tn[4];
#pragma unroll
        for (int j = 0; j < 4; ++j) tn[j] = Fp[(size_t)(mn + j) * DIM];
#pragma unroll
        for (int j = 0; j < 4; ++j) {
            const float* as = asld + (mi + j) * KC;
            float t = tb[j];
#pragma unroll
            for (int k = 0; k < KC; k += 4) {
                float4 a4 = *(const float4*)(as + k);
                acc[k]     += a4.x * t;
                acc[k + 1] += a4.y * t;
                acc[k + 2] += a4.z * t;
                acc[k + 3] += a4.w * t;
            }
        }
#pragma unroll
        for (int j = 0; j < 4; ++j) tb[j] = tn[j];
    }

    if (twoStage) {
        float* P = outP + (size_t)blockIdx.x * (KC * DIM);
#pragma unroll
        for (int k = 0; k < KC; ++k) P[k * DIM + dd] = acc[k];
    } else {
        for (int k = 0; k < KC; ++k) atomicAdd(&outP[k * DIM + dd], acc[k]);
    }
}

// ---------------- R2: reduce the 256 partials -> weighted -------------------------
__global__ __launch_bounds__(128) void k_reducep(const float* __restrict__ P,
                                                 float* __restrict__ W, int G) {
    int o = blockIdx.x * 128 + threadIdx.x;  // 0..49151
    const float* p = P + o;
    float s0 = 0.f, s1 = 0.f, s2 = 0.f, s3 = 0.f;
    size_t stride = (size_t)KC * DIM;
#pragma unroll 4
    for (int g = 0; g < G; g += 4) {
        s0 += p[(size_t)g * stride];
        s1 += p[(size_t)(g + 1) * stride];
        s2 += p[(size_t)(g + 2) * stride];
        s3 += p[(size_t)(g + 3) * stride];
    }
    W[o] = (s0 + s1) + (s2 + s3);
}

// ---------------- K4: finalize centers (normalize, EMA, normalize) ----------------
__global__ __launch_bounds__(256) void k_final(const float* __restrict__ W,
                                               const float* __restrict__ mass,
                                               const float* __restrict__ cn,
                                               float* __restrict__ outC) {
    int k = blockIdx.x, tid = threadIdx.x;
    float mk = fmaxf(mass[k], 1e-6f);
    float w0 = W[k * DIM + tid] / mk;
    float w1 = W[k * DIM + tid + 256] / mk;
    float w2 = W[k * DIM + tid + 512] / mk;
    float ss = w0 * w0 + w1 * w1 + w2 * w2;
    __shared__ float red[4];
    for (int o = 32; o; o >>= 1) ss += __shfl_xor(ss, o);
    if ((tid & 63) == 0) red[tid >> 6] = ss;
    __syncthreads();
    ss = red[0] + red[1] + red[2] + red[3];
    float n1 = fmaxf(sqrtf(ss), 1e-12f);

    float u0 = 0.99f * cn[k * DIM + tid]        + 0.01f * (w0 / n1);
    float u1 = 0.99f * cn[k * DIM + tid + 256]  + 0.01f * (w1 / n1);
    float u2 = 0.99f * cn[k * DIM + tid + 512]  + 0.01f * (w2 / n1);
    float ss2 = u0 * u0 + u1 * u1 + u2 * u2;
    __syncthreads();
    for (int o = 32; o; o >>= 1) ss2 += __shfl_xor(ss2, o);
    if ((tid & 63) == 0) red[tid >> 6] = ss2;
    __syncthreads();
    ss2 = red[0] + red[1] + red[2] + red[3];
    float n2 = fmaxf(sqrtf(ss2), 1e-12f);

    outC[k * DIM + tid]       = u0 / n2;
    outC[k * DIM + tid + 256] = u1 / n2;
    outC[k * DIM + tid + 512] = u2 / n2;
}

extern "C" void kernel_launch(void* const* d_in, const int* in_sizes, int n_in,
                              void* d_out, int out_size, void* d_ws, size_t ws_size,
                              hipStream_t stream) {
    const float* F = (const float*)d_in[0];        // [65536][768]
    const float* centers = (const float*)d_in[1];  // [64][768]
    float* out = (float*)d_out;
    float* A = out;                                 // assignments [65536][64]
    float* outC = out + (size_t)M_TOTAL * KC;       // updated centers [64][768]

    float* w = (float*)d_ws;
    float* cn       = w;                        // 49152
    short* cnbf     = (short*)(w + 49152);      // 49152 shorts (24576 float slots)
    float* weighted = w + 73728;                // 49152
    float* sr0      = w + 122880;               // 64
    float* sr1      = sr0 + 64;
    float* sr2      = sr0 + 128;
    float* mass     = sr0 + 192;
    float* R        = sr0 + 256;
    float* invn     = w + 131072;               // 65536
    float* cbuf     = w + 196608;               // 65536
    float* E        = w + 262144;               // 4194304
    float* partial  = w + 4456448;              // 256*49152 (if ws allows)

    int twoStage = (ws_size >= (size_t)(4456448 + 256 * 49152) * sizeof(float));

    // zero accumulators: weighted + sr0/sr1/sr2/mass
    hipMemsetAsync(weighted, 0, (size_t)(49152 + 256) * sizeof(float), stream);

    k_centers<<<KC, 256, 0, stream>>>(centers, cn, cnbf);
    k_logits<<<M_TOTAL / 64, 256, 0, stream>>>(F, cnbf, E, invn, sr0);
    k_t1<<<1, 64, 0, stream>>>(sr0, R);
    k_sink<0><<<1024, 256, 0, stream>>>(E, R, cbuf, sr1, A, mass);
    k_t23<<<1, 64, 0, stream>>>(sr1, R);
    k_sink<1><<<1024, 256, 0, stream>>>(E, R, cbuf, sr2, A, mass);
    k_t23<<<1, 64, 0, stream>>>(sr2, R);
    k_sink<2><<<1024, 256, 0, stream>>>(E, R, cbuf, nullptr, A, mass);

    k_weighted<<<256, 768, 0, stream>>>(F, A, invn, twoStage ? partial : weighted, twoStage);
    if (twoStage) k_reducep<<<384, 128, 0, stream>>>(partial, weighted, 256);
    k_final<<<KC, 256, 0, stream>>>(weighted, mass, cn, outC);
}

// Round 2
// 313.169 us; speedup vs baseline: 1.3775x; 1.3775x over previous
//
#include <hip/hip_runtime.h>
#include <hip/hip_bf16.h>

#define M_TOTAL 65536
#define DIM 768
#define KC 64
#define INV_T 10.0f

typedef __attribute__((ext_vector_type(4))) float f32x4;
typedef __attribute__((ext_vector_type(8))) short bf16x8;

__device__ __forceinline__ short f2bf(float f) {
    __hip_bfloat16 h = __float2bfloat16(f);   // RNE; compiler fuses pairs to v_cvt_pk_bf16_f32
    union { __hip_bfloat16 h; short s; } u; u.h = h;
    return u.s;
}

// ---------------- K0: normalize centers -> cn (fp32) + cnbf (bf16) ----------------
__global__ __launch_bounds__(256) void k_centers(const float* __restrict__ centers,
                                                 float* __restrict__ cn,
                                                 short* __restrict__ cnbf) {
    int k = blockIdx.x, tid = threadIdx.x;
    float ss = 0.f;
    for (int i = tid; i < DIM; i += 256) { float v = centers[k * DIM + i]; ss += v * v; }
    __shared__ float red[4];
    for (int o = 32; o; o >>= 1) ss += __shfl_xor(ss, o);
    if ((tid & 63) == 0) red[tid >> 6] = ss;
    __syncthreads();
    ss = red[0] + red[1] + red[2] + red[3];
    float inv = 1.0f / fmaxf(sqrtf(ss), 1e-12f);
    for (int i = tid; i < DIM; i += 256) {
        float v = centers[k * DIM + i] * inv;
        cn[k * DIM + i] = v;
        cnbf[k * DIM + i] = f2bf(v);
    }
}

// ---------------- K1: logits GEMM (bf16 MFMA) + exp -> E, invnorm, col sums -------
__global__ __launch_bounds__(256) void k_logits(const float* __restrict__ F,
                                                const short* __restrict__ cnbf,
                                                float* __restrict__ E,
                                                float* __restrict__ invn,
                                                float* __restrict__ sr0) {
    int tid = threadIdx.x;
    int wave = tid >> 6, lane = tid & 63;
    int l15 = lane & 15, lhi = lane >> 4;
    int rowbase = blockIdx.x * 64 + wave * 16;

    const float* Arow = F + (size_t)(rowbase + l15) * DIM + lhi * 8;
    const short* Bbase = cnbf + (size_t)l15 * DIM + lhi * 8;

    f32x4 acc[4];
#pragma unroll
    for (int n = 0; n < 4; ++n) acc[n] = (f32x4){0.f, 0.f, 0.f, 0.f};
    float ss = 0.f;

#pragma unroll
    for (int kb = 0; kb < DIM; kb += 32) {
        float4 a0 = *(const float4*)(Arow + kb);
        float4 a1 = *(const float4*)(Arow + kb + 4);
        ss += a0.x * a0.x + a0.y * a0.y + a0.z * a0.z + a0.w * a0.w;
        ss += a1.x * a1.x + a1.y * a1.y + a1.z * a1.z + a1.w * a1.w;
        bf16x8 af;
        af[0] = f2bf(a0.x); af[1] = f2bf(a0.y); af[2] = f2bf(a0.z); af[3] = f2bf(a0.w);
        af[4] = f2bf(a1.x); af[5] = f2bf(a1.y); af[6] = f2bf(a1.z); af[7] = f2bf(a1.w);
#pragma unroll
        for (int n = 0; n < 4; ++n) {
            bf16x8 b = *(const bf16x8*)(Bbase + (size_t)n * 16 * DIM + kb);
            acc[n] = __builtin_amdgcn_mfma_f32_16x16x32_bf16(af, b, acc[n], 0, 0, 0);
        }
    }

    ss += __shfl_xor(ss, 16);
    ss += __shfl_xor(ss, 32);
    float inv = 1.0f / fmaxf(sqrtf(ss), 1e-12f);
    if (lane < 16) invn[rowbase + lane] = inv;

    float sc[4];
#pragma unroll
    for (int j = 0; j < 4; ++j) sc[j] = __shfl(inv, lhi * 4 + j) * INV_T;

    float colp[4] = {0.f, 0.f, 0.f, 0.f};
#pragma unroll
    for (int n = 0; n < 4; ++n) {
#pragma unroll
        for (int j = 0; j < 4; ++j) {
            float e = expf(acc[n][j] * sc[j]);
            E[(size_t)(rowbase + lhi * 4 + j) * KC + n * 16 + l15] = e;
            colp[n] += e;
        }
    }
#pragma unroll
    for (int n = 0; n < 4; ++n) {
        colp[n] += __shfl_xor(colp[n], 16);
        colp[n] += __shfl_xor(colp[n], 32);
    }
    __shared__ float bsr[KC];
    if (tid < KC) bsr[tid] = 0.f;
    __syncthreads();
    if (lane < 16) {
#pragma unroll
        for (int n = 0; n < 4; ++n) atomicAdd(&bsr[n * 16 + lane], colp[n]);
    }
    __syncthreads();
    if (tid < KC) atomicAdd(&sr0[tid], bsr[tid]);
}

// ---------------- P: fused R-chain + col-step + next row-step accumulation --------
// R recomputed redundantly per wave from sr0/sr1/sr2 (removes the tiny k_t kernels).
// MODE 0: c_old = 1, writes c, accumulates srNext(=sr1)
// MODE 1: reads/writes c, accumulates srNext(=sr2)
// MODE 2: final col step -> writes assignments + mass; scales E in-place by a*invn
template <int MODE>
__global__ __launch_bounds__(256) void k_sink(float* __restrict__ E,
                                              const float* __restrict__ sr0,
                                              const float* __restrict__ sr1,
                                              const float* __restrict__ sr2,
                                              const float* __restrict__ invn,
                                              float* __restrict__ c,
                                              float* __restrict__ srNext,
                                              float* __restrict__ Aout,
                                              float* __restrict__ mass) {
    int tid = threadIdx.x, lane = tid & 63;
    // R-chain (exact replica of the old k_t1/k_t23 math)
    float s0 = sr0[lane];
    float tot = s0;
    for (int o = 32; o; o >>= 1) tot += __shfl_xor(tot, o);
    float S = fmaxf(tot, 1e-12f);
    float Rl = (1.0f / S) / (fmaxf(s0 / S, 1e-12f) * 64.0f);
    if (MODE >= 1) Rl = Rl / (fmaxf(Rl * sr1[lane], 1e-12f) * 64.0f);
    if (MODE >= 2) Rl = Rl / (fmaxf(Rl * sr2[lane], 1e-12f) * 64.0f);

    int gw = blockIdx.x * 4 + (tid >> 6);
    float wacc = 0.f;
    int m0 = gw * 16;
    for (int i = 0; i < 16; ++i) {
        int m = m0 + i;
        size_t idx = (size_t)m * KC + lane;
        float e = E[idx];
        float v = e * Rl;
        float s = v;
        for (int o = 32; o; o >>= 1) s += __shfl_xor(s, o);
        float cold = (MODE == 0) ? 1.0f : c[m];
        float cs = cold * s;
        float cnew = cold / (fmaxf(cs, 1e-12f) * 65536.0f);
        if (MODE == 2) {
            float a = v * cnew * 65536.0f;
            Aout[idx] = a;
            E[idx] = a * invn[m];  // pre-scaled Q for k_weighted, in-place
            wacc += a;
        } else {
            if (lane == 0) c[m] = cnew;
            wacc += e * cnew;
        }
    }
    __shared__ float bacc[KC];
    if (tid < KC) bacc[tid] = 0.f;
    __syncthreads();
    atomicAdd(&bacc[lane], wacc);
    __syncthreads();
    if (tid < KC) atomicAdd((MODE == 2 ? mass : srNext) + tid, bacc[tid]);
}

// ---------------- K3: weighted centers, fp32, wave-uniform Q loads ----------------
// weighted[k][dd] = sum_m Qs[m][k] * F[m][dd], Qs = E (pre-scaled by invn in sink<2>).
// Block: 768 threads = one dd column each, 64 k-accumulators in VGPRs (all static
// indexing -> no scratch). Q-row loads are block-uniform -> scalar path.
__global__ __launch_bounds__(768) void k_weighted(const float* __restrict__ F,
                                                  const float* __restrict__ Qs,
                                                  float* __restrict__ P) {
    int tid = threadIdx.x;
    int mb = blockIdx.x * 256;
    float acc[KC];
#pragma unroll
    for (int k = 0; k < KC; ++k) acc[k] = 0.f;

    const float* Fp = F + (size_t)mb * DIM + tid;
    const float* Qp = Qs + (size_t)mb * KC;

    for (int mi = 0; mi < 256; ++mi) {
        float t = Fp[(size_t)mi * DIM];
        const float4* q4 = (const float4*)(Qp + mi * KC);
#pragma unroll
        for (int k = 0; k < KC; k += 4) {
            float4 a4 = q4[k >> 2];
            acc[k]     += a4.x * t;
            acc[k + 1] += a4.y * t;
            acc[k + 2] += a4.z * t;
            acc[k + 3] += a4.w * t;
        }
    }

    float* Pb = P + (size_t)blockIdx.x * (KC * DIM) + tid;
#pragma unroll
    for (int k = 0; k < KC; ++k) Pb[(size_t)k * DIM] = acc[k];
}

// ---------------- R2: reduce the 256 partials -> weighted -------------------------
__global__ __launch_bounds__(128) void k_reducep(const float* __restrict__ P,
                                                 float* __restrict__ W, int G) {
    int o = blockIdx.x * 128 + threadIdx.x;  // 0..49151
    const float* p = P + o;
    float s0 = 0.f, s1 = 0.f, s2 = 0.f, s3 = 0.f;
    size_t stride = (size_t)KC * DIM;
#pragma unroll 4
    for (int g = 0; g < G; g += 4) {
        s0 += p[(size_t)g * stride];
        s1 += p[(size_t)(g + 1) * stride];
        s2 += p[(size_t)(g + 2) * stride];
        s3 += p[(size_t)(g + 3) * stride];
    }
    W[o] = (s0 + s1) + (s2 + s3);
}

// ---------------- K4: finalize centers (normalize, EMA, normalize) ----------------
__global__ __launch_bounds__(256) void k_final(const float* __restrict__ W,
                                               const float* __restrict__ mass,
                                               const float* __restrict__ cn,
                                               float* __restrict__ outC) {
    int k = blockIdx.x, tid = threadIdx.x;
    float mk = fmaxf(mass[k], 1e-6f);
    float w0 = W[k * DIM + tid] / mk;
    float w1 = W[k * DIM + tid + 256] / mk;
    float w2 = W[k * DIM + tid + 512] / mk;
    float ss = w0 * w0 + w1 * w1 + w2 * w2;
    __shared__ float red[4];
    for (int o = 32; o; o >>= 1) ss += __shfl_xor(ss, o);
    if ((tid & 63) == 0) red[tid >> 6] = ss;
    __syncthreads();
    ss = red[0] + red[1] + red[2] + red[3];
    float n1 = fmaxf(sqrtf(ss), 1e-12f);

    float u0 = 0.99f * cn[k * DIM + tid]        + 0.01f * (w0 / n1);
    float u1 = 0.99f * cn[k * DIM + tid + 256]  + 0.01f * (w1 / n1);
    float u2 = 0.99f * cn[k * DIM + tid + 512]  + 0.01f * (w2 / n1);
    float ss2 = u0 * u0 + u1 * u1 + u2 * u2;
    __syncthreads();
    for (int o = 32; o; o >>= 1) ss2 += __shfl_xor(ss2, o);
    if ((tid & 63) == 0) red[tid >> 6] = ss2;
    __syncthreads();
    ss2 = red[0] + red[1] + red[2] + red[3];
    float n2 = fmaxf(sqrtf(ss2), 1e-12f);

    outC[k * DIM + tid]       = u0 / n2;
    outC[k * DIM + tid + 256] = u1 / n2;
    outC[k * DIM + tid + 512] = u2 / n2;
}

extern "C" void kernel_launch(void* const* d_in, const int* in_sizes, int n_in,
                              void* d_out, int out_size, void* d_ws, size_t ws_size,
                              hipStream_t stream) {
    const float* F = (const float*)d_in[0];        // [65536][768]
    const float* centers = (const float*)d_in[1];  // [64][768]
    float* out = (float*)d_out;
    float* A = out;                                 // assignments [65536][64]
    float* outC = out + (size_t)M_TOTAL * KC;       // updated centers [64][768]

    float* w = (float*)d_ws;
    float* cn       = w;                        // 49152
    short* cnbf     = (short*)(w + 49152);      // 49152 shorts (24576 float slots)
    float* weighted = w + 73728;                // 49152
    float* sr0      = w + 122880;               // 64
    float* sr1      = sr0 + 64;
    float* sr2      = sr0 + 128;
    float* mass     = sr0 + 192;
    float* invn     = w + 131072;               // 65536
    float* cbuf     = w + 196608;               // 65536
    float* E        = w + 262144;               // 4194304 (becomes Qs after sink<2>)
    float* partial  = w + 4456448;              // 256*49152  (ws >= 68.2 MB proven in R1)

    // zero accumulators: weighted + sr0/sr1/sr2/mass
    hipMemsetAsync(weighted, 0, (size_t)(49152 + 256) * sizeof(float), stream);

    k_centers<<<KC, 256, 0, stream>>>(centers, cn, cnbf);
    k_logits<<<M_TOTAL / 64, 256, 0, stream>>>(F, cnbf, E, invn, sr0);
    k_sink<0><<<1024, 256, 0, stream>>>(E, sr0, sr1, sr2, invn, cbuf, sr1, A, mass);
    k_sink<1><<<1024, 256, 0, stream>>>(E, sr0, sr1, sr2, invn, cbuf, sr2, A, mass);
    k_sink<2><<<1024, 256, 0, stream>>>(E, sr0, sr1, sr2, invn, cbuf, nullptr, A, mass);

    k_weighted<<<256, 768, 0, stream>>>(F, E, partial);
    k_reducep<<<384, 128, 0, stream>>>(partial, weighted, 256);
    k_final<<<KC, 256, 0, stream>>>(weighted, mass, cn, outC);
}

// Round 3
// 238.739 us; speedup vs baseline: 1.8070x; 1.3118x over previous
//
#include <hip/hip_runtime.h>
#include <hip/hip_bf16.h>

#define M_TOTAL 65536
#define DIM 768
#define KC 64
#define INV_T 10.0f

// k_weighted tiling
#define DT 128   // d-cols per block
#define MB 64    // m per LDS chunk
#define CH 16    // chunks per block (m-range 1024)
#define MSEG 64  // m-segments (partials)

typedef __attribute__((ext_vector_type(4))) float f32x4;
typedef __attribute__((ext_vector_type(8))) short bf16x8;
typedef __attribute__((ext_vector_type(4))) unsigned short u16x4;

__device__ __forceinline__ short f2bf(float f) {
    __hip_bfloat16 h = __float2bfloat16(f);
    union { __hip_bfloat16 h; short s; } u; u.h = h;
    return u.s;
}

// ---------------- K0: normalize centers -> cn (fp32) + cnbf (bf16); zero sums ----
__global__ __launch_bounds__(256) void k_centers(const float* __restrict__ centers,
                                                 float* __restrict__ cn,
                                                 short* __restrict__ cnbf,
                                                 float* __restrict__ srz) {
    int k = blockIdx.x, tid = threadIdx.x;
    if (k == 0) srz[tid] = 0.f;  // sr0,sr1,sr2,mass (256 floats contiguous)
    float ss = 0.f;
    for (int i = tid; i < DIM; i += 256) { float v = centers[k * DIM + i]; ss += v * v; }
    __shared__ float red[4];
    for (int o = 32; o; o >>= 1) ss += __shfl_xor(ss, o);
    if ((tid & 63) == 0) red[tid >> 6] = ss;
    __syncthreads();
    ss = red[0] + red[1] + red[2] + red[3];
    float inv = 1.0f / fmaxf(sqrtf(ss), 1e-12f);
    for (int i = tid; i < DIM; i += 256) {
        float v = centers[k * DIM + i] * inv;
        cn[k * DIM + i] = v;
        cnbf[k * DIM + i] = f2bf(v);
    }
}

// ---------------- K1: logits GEMM (bf16 MFMA) + exp -> E, Fbf, invn, sr0 ----------
__global__ __launch_bounds__(256) void k_logits(const float* __restrict__ F,
                                                const short* __restrict__ cnbf,
                                                float* __restrict__ E,
                                                short* __restrict__ Fbf,
                                                float* __restrict__ invn,
                                                float* __restrict__ sr0) {
    int tid = threadIdx.x;
    int wave = tid >> 6, lane = tid & 63;
    int l15 = lane & 15, lhi = lane >> 4;
    int rowbase = blockIdx.x * 64 + wave * 16;

    const float* Arow = F + (size_t)(rowbase + l15) * DIM + lhi * 8;
    short* Frow = Fbf + (size_t)(rowbase + l15) * DIM + lhi * 8;
    const short* Bbase = cnbf + (size_t)l15 * DIM + lhi * 8;

    f32x4 acc[4];
#pragma unroll
    for (int n = 0; n < 4; ++n) acc[n] = (f32x4){0.f, 0.f, 0.f, 0.f};
    float ss = 0.f;

#pragma unroll
    for (int kb = 0; kb < DIM; kb += 32) {
        float4 a0 = *(const float4*)(Arow + kb);
        float4 a1 = *(const float4*)(Arow + kb + 4);
        ss += a0.x * a0.x + a0.y * a0.y + a0.z * a0.z + a0.w * a0.w;
        ss += a1.x * a1.x + a1.y * a1.y + a1.z * a1.z + a1.w * a1.w;
        bf16x8 af;
        af[0] = f2bf(a0.x); af[1] = f2bf(a0.y); af[2] = f2bf(a0.z); af[3] = f2bf(a0.w);
        af[4] = f2bf(a1.x); af[5] = f2bf(a1.y); af[6] = f2bf(a1.z); af[7] = f2bf(a1.w);
        *(bf16x8*)(Frow + kb) = af;  // bf16 copy of F for k_weighted
#pragma unroll
        for (int n = 0; n < 4; ++n) {
            bf16x8 b = *(const bf16x8*)(Bbase + (size_t)n * 16 * DIM + kb);
            acc[n] = __builtin_amdgcn_mfma_f32_16x16x32_bf16(af, b, acc[n], 0, 0, 0);
        }
    }

    ss += __shfl_xor(ss, 16);
    ss += __shfl_xor(ss, 32);
    float inv = 1.0f / fmaxf(sqrtf(ss), 1e-12f);
    if (lane < 16) invn[rowbase + lane] = inv;

    float sc[4];
#pragma unroll
    for (int j = 0; j < 4; ++j) sc[j] = __shfl(inv, lhi * 4 + j) * INV_T;

    float colp[4] = {0.f, 0.f, 0.f, 0.f};
#pragma unroll
    for (int n = 0; n < 4; ++n) {
#pragma unroll
        for (int j = 0; j < 4; ++j) {
            float e = expf(acc[n][j] * sc[j]);
            E[(size_t)(rowbase + lhi * 4 + j) * KC + n * 16 + l15] = e;
            colp[n] += e;
        }
    }
#pragma unroll
    for (int n = 0; n < 4; ++n) {
        colp[n] += __shfl_xor(colp[n], 16);
        colp[n] += __shfl_xor(colp[n], 32);
    }
    __shared__ float bsr[KC];
    if (tid < KC) bsr[tid] = 0.f;
    __syncthreads();
    if (lane < 16) {
#pragma unroll
        for (int n = 0; n < 4; ++n) atomicAdd(&bsr[n * 16 + lane], colp[n]);
    }
    __syncthreads();
    if (tid < KC) atomicAdd(&sr0[tid], bsr[tid]);
}

// ---------------- P: fused R-chain + col-step + next row-step accumulation --------
template <int MODE>
__global__ __launch_bounds__(256) void k_sink(const float* __restrict__ E,
                                              const float* __restrict__ sr0,
                                              const float* __restrict__ sr1,
                                              const float* __restrict__ sr2,
                                              const float* __restrict__ invn,
                                              float* __restrict__ c,
                                              float* __restrict__ srNext,
                                              float* __restrict__ Aout,
                                              short* __restrict__ Qbf,
                                              float* __restrict__ mass) {
    int tid = threadIdx.x, lane = tid & 63;
    // R-chain (replica of the iteration scale math)
    float s0 = sr0[lane];
    float tot = s0;
    for (int o = 32; o; o >>= 1) tot += __shfl_xor(tot, o);
    float S = fmaxf(tot, 1e-12f);
    float Rl = (1.0f / S) / (fmaxf(s0 / S, 1e-12f) * 64.0f);
    if (MODE >= 1) Rl = Rl / (fmaxf(Rl * sr1[lane], 1e-12f) * 64.0f);
    if (MODE >= 2) Rl = Rl / (fmaxf(Rl * sr2[lane], 1e-12f) * 64.0f);

    int gw = blockIdx.x * 4 + (tid >> 6);
    float wacc = 0.f;
    int m0 = gw * 16;
    for (int i = 0; i < 16; i += 4) {  // 4-row ILP on the shuffle chains
        float e[4], v[4], s[4];
#pragma unroll
        for (int j = 0; j < 4; ++j) e[j] = E[(size_t)(m0 + i + j) * KC + lane];
#pragma unroll
        for (int j = 0; j < 4; ++j) { v[j] = e[j] * Rl; s[j] = v[j]; }
        for (int o = 32; o; o >>= 1) {
#pragma unroll
            for (int j = 0; j < 4; ++j) s[j] += __shfl_xor(s[j], o);
        }
#pragma unroll
        for (int j = 0; j < 4; ++j) {
            int m = m0 + i + j;
            float cold = (MODE == 0) ? 1.0f : c[m];
            float cnew = cold / (fmaxf(cold * s[j], 1e-12f) * 65536.0f);
            if (MODE == 2) {
                float a = v[j] * cnew * 65536.0f;
                size_t idx = (size_t)m * KC + lane;
                Aout[idx] = a;
                Qbf[idx] = f2bf(a * invn[m]);
                wacc += a;
            } else {
                if (lane == 0) c[m] = cnew;
                wacc += e[j] * cnew;
            }
        }
    }
    __shared__ float bacc[KC];
    if (tid < KC) bacc[tid] = 0.f;
    __syncthreads();
    atomicAdd(&bacc[lane], wacc);
    __syncthreads();
    if (tid < KC) atomicAdd((MODE == 2 ? mass : srNext) + tid, bacc[tid]);
}

// ---------------- K3: weighted centers — bf16 MFMA GEMM ---------------------------
// P[ms][k][d] = sum_{m in seg} Qbf[m][k] * Fbf[m][d]. Block = 64k x 128d tile,
// 4 waves, LDS-staged transposed tiles ([k][m],[d][m]) with XOR swizzle (G4).
__global__ __launch_bounds__(256) void k_weighted(const short* __restrict__ Fbf,
                                                  const short* __restrict__ Qbf,
                                                  float* __restrict__ P) {
    __shared__ short ldsF[DT * MB];  // [d][m] swizzled, 16 KiB
    __shared__ short ldsQ[KC * MB];  // [k][m] swizzled, 8 KiB
    int tid = threadIdx.x;
    int dt = blockIdx.x;  // 0..5
    int ms = blockIdx.y;  // 0..MSEG-1
    int wave = tid >> 6, lane = tid & 63;
    int l15 = lane & 15, lhi = lane >> 4;

    int m0 = ms * (MB * CH);
    int d0 = dt * DT;

    f32x4 acc[4][2];
#pragma unroll
    for (int kt = 0; kt < 4; ++kt)
#pragma unroll
        for (int ds = 0; ds < 2; ++ds) acc[kt][ds] = (f32x4){0.f, 0.f, 0.f, 0.f};

    // staging thread mappings (coalesced 8B loads)
    int f_dq = (tid & 31) * 4;        // d 0..124
    int f_m8 = (tid >> 5) * 8;        // m 0..56
    int q_kq = (tid & 15) * 4;        // k 0..60   (threads <128)
    int q_m8 = ((tid >> 4) & 7) * 8;  // m 0..56

    for (int ch = 0; ch < CH; ++ch) {
        int mb = m0 + ch * MB;
        // ---- stage F tile (transpose-pack into [d][m]) ----
        u16x4 r[8];
#pragma unroll
        for (int j = 0; j < 8; ++j)
            r[j] = *(const u16x4*)(Fbf + (size_t)(mb + f_m8 + j) * DIM + d0 + f_dq);
        // ---- stage Q tile ----
        u16x4 q[8];
        if (tid < 128) {
#pragma unroll
            for (int j = 0; j < 8; ++j)
                q[j] = *(const u16x4*)(Qbf + (size_t)(mb + q_m8 + j) * KC + q_kq);
        }
        __syncthreads();  // previous chunk's reads done before overwrite
#pragma unroll
        for (int i = 0; i < 4; ++i) {
            int d = f_dq + i;
            uint4 w;
            w.x = (unsigned)r[0][i] | ((unsigned)r[1][i] << 16);
            w.y = (unsigned)r[2][i] | ((unsigned)r[3][i] << 16);
            w.z = (unsigned)r[4][i] | ((unsigned)r[5][i] << 16);
            w.w = (unsigned)r[6][i] | ((unsigned)r[7][i] << 16);
            int byte = (d * (MB * 2) + f_m8 * 2) ^ ((d & 7) << 4);
            *(uint4*)((char*)ldsF + byte) = w;
        }
        if (tid < 128) {
#pragma unroll
            for (int i = 0; i < 4; ++i) {
                int k = q_kq + i;
                uint4 w;
                w.x = (unsigned)q[0][i] | ((unsigned)q[1][i] << 16);
                w.y = (unsigned)q[2][i] | ((unsigned)q[3][i] << 16);
                w.z = (unsigned)q[4][i] | ((unsigned)q[5][i] << 16);
                w.w = (unsigned)q[6][i] | ((unsigned)q[7][i] << 16);
                int byte = (k * (MB * 2) + q_m8 * 2) ^ ((k & 7) << 4);
                *(uint4*)((char*)ldsQ + byte) = w;
            }
        }
        __syncthreads();
        // ---- compute: 2 m-halves x 4 ktiles x 2 dsubs ----
#pragma unroll
        for (int h = 0; h < 2; ++h) {
            bf16x8 afr[4];
#pragma unroll
            for (int kt = 0; kt < 4; ++kt) {
                int k = kt * 16 + l15;
                int byte = (k * (MB * 2) + (h * 32 + lhi * 8) * 2) ^ ((k & 7) << 4);
                afr[kt] = *(bf16x8*)((char*)ldsQ + byte);
            }
#pragma unroll
            for (int ds = 0; ds < 2; ++ds) {
                int d = wave * 32 + ds * 16 + l15;
                int byte = (d * (MB * 2) + (h * 32 + lhi * 8) * 2) ^ ((d & 7) << 4);
                bf16x8 bfr = *(bf16x8*)((char*)ldsF + byte);
#pragma unroll
                for (int kt = 0; kt < 4; ++kt)
                    acc[kt][ds] = __builtin_amdgcn_mfma_f32_16x16x32_bf16(afr[kt], bfr, acc[kt][ds], 0, 0, 0);
            }
        }
        __syncthreads();
    }

    float* Pb = P + (size_t)ms * (KC * DIM) + d0;
#pragma unroll
    for (int kt = 0; kt < 4; ++kt)
#pragma unroll
        for (int ds = 0; ds < 2; ++ds) {
            int d = wave * 32 + ds * 16 + l15;
#pragma unroll
            for (int r4 = 0; r4 < 4; ++r4) {
                int k = kt * 16 + lhi * 4 + r4;
                Pb[(size_t)k * DIM + d] = acc[kt][ds][r4];
            }
        }
}

// ---------------- K4: reduce partials + finalize centers --------------------------
__global__ __launch_bounds__(256) void k_final(const float* __restrict__ P,
                                               const float* __restrict__ mass,
                                               const float* __restrict__ cn,
                                               float* __restrict__ outC) {
    int k = blockIdx.x, tid = threadIdx.x;
    float mk = fmaxf(mass[k], 1e-6f);
    float w[3];
#pragma unroll
    for (int g = 0; g < 3; ++g) {
        int d = tid + g * 256;
        float s0 = 0.f, s1 = 0.f, s2 = 0.f, s3 = 0.f;
        const float* p = P + (size_t)k * DIM + d;
#pragma unroll 4
        for (int msg = 0; msg < MSEG; msg += 4) {
            s0 += p[(size_t)msg * (KC * DIM)];
            s1 += p[(size_t)(msg + 1) * (KC * DIM)];
            s2 += p[(size_t)(msg + 2) * (KC * DIM)];
            s3 += p[(size_t)(msg + 3) * (KC * DIM)];
        }
        w[g] = ((s0 + s1) + (s2 + s3)) / mk;
    }
    float ss = w[0] * w[0] + w[1] * w[1] + w[2] * w[2];
    __shared__ float red[4];
    for (int o = 32; o; o >>= 1) ss += __shfl_xor(ss, o);
    if ((tid & 63) == 0) red[tid >> 6] = ss;
    __syncthreads();
    ss = red[0] + red[1] + red[2] + red[3];
    float n1 = fmaxf(sqrtf(ss), 1e-12f);

    float u0 = 0.99f * cn[k * DIM + tid]       + 0.01f * (w[0] / n1);
    float u1 = 0.99f * cn[k * DIM + tid + 256] + 0.01f * (w[1] / n1);
    float u2 = 0.99f * cn[k * DIM + tid + 512] + 0.01f * (w[2] / n1);
    float ss2 = u0 * u0 + u1 * u1 + u2 * u2;
    __syncthreads();
    for (int o = 32; o; o >>= 1) ss2 += __shfl_xor(ss2, o);
    if ((tid & 63) == 0) red[tid >> 6] = ss2;
    __syncthreads();
    ss2 = red[0] + red[1] + red[2] + red[3];
    float n2 = fmaxf(sqrtf(ss2), 1e-12f);

    outC[k * DIM + tid]       = u0 / n2;
    outC[k * DIM + tid + 256] = u1 / n2;
    outC[k * DIM + tid + 512] = u2 / n2;
}

extern "C" void kernel_launch(void* const* d_in, const int* in_sizes, int n_in,
                              void* d_out, int out_size, void* d_ws, size_t ws_size,
                              hipStream_t stream) {
    const float* F = (const float*)d_in[0];        // [65536][768]
    const float* centers = (const float*)d_in[1];  // [64][768]
    float* out = (float*)d_out;
    float* A = out;                                 // assignments [65536][64]
    float* outC = out + (size_t)M_TOTAL * KC;       // updated centers [64][768]

    float* w = (float*)d_ws;                        // ws = 768 MiB (poison fill evidence)
    float* cn   = w;                                // 49152
    short* cnbf = (short*)(w + 49152);              // 24576 float slots
    float* sr0  = w + 73728;                        // sr0,sr1,sr2,mass: 256 floats
    float* sr1  = sr0 + 64;
    float* sr2  = sr0 + 128;
    float* mass = sr0 + 192;
    float* invn = w + 73984;                        // 65536
    float* cbuf = w + 139520;                       // 65536
    float* E    = w + 205056;                       // 4194304
    short* Fbf  = (short*)(w + 4399360);            // 50331648 shorts (96 MiB)
    short* Qbf  = (short*)(w + 29565184);           // 4194304 shorts (8 MiB)
    float* partial = w + 31662336;                  // MSEG*64*768 = 3145728 (12 MiB)

    k_centers<<<KC, 256, 0, stream>>>(centers, cn, cnbf, sr0);
    k_logits<<<M_TOTAL / 64, 256, 0, stream>>>(F, cnbf, E, Fbf, invn, sr0);
    k_sink<0><<<1024, 256, 0, stream>>>(E, sr0, sr1, sr2, invn, cbuf, sr1, A, Qbf, mass);
    k_sink<1><<<1024, 256, 0, stream>>>(E, sr0, sr1, sr2, invn, cbuf, sr2, A, Qbf, mass);
    k_sink<2><<<1024, 256, 0, stream>>>(E, sr0, sr1, sr2, invn, cbuf, nullptr, A, Qbf, mass);

    dim3 wgrid(DIM / DT, MSEG);
    k_weighted<<<wgrid, 256, 0, stream>>>(Fbf, Qbf, partial);
    k_final<<<KC, 256, 0, stream>>>(partial, mass, cn, outC);
}

// Round 4
// 231.637 us; speedup vs baseline: 1.8624x; 1.0307x over previous
//
#include <hip/hip_runtime.h>
#include <hip/hip_bf16.h>

#define M_TOTAL 65536
#define DIM 768
#define KC 64
#define INV_T 10.0f

// k_weighted tiling
#define DT 128   // d-cols per block
#define MB 64    // m per LDS chunk
#define CH 16    // chunks per block (m-range 1024)
#define MSEG 64  // m-segments (partials)

typedef __attribute__((ext_vector_type(4))) float f32x4;
typedef __attribute__((ext_vector_type(8))) short bf16x8;
typedef __attribute__((ext_vector_type(4))) unsigned short u16x4;

__device__ __forceinline__ short f2bf(float f) {
    __hip_bfloat16 h = __float2bfloat16(f);
    union { __hip_bfloat16 h; short s; } u; u.h = h;
    return u.s;
}

// ---------------- K0: normalize centers -> cn (fp32) + cnbf (bf16); zero sums ----
__global__ __launch_bounds__(256) void k_centers(const float* __restrict__ centers,
                                                 float* __restrict__ cn,
                                                 short* __restrict__ cnbf,
                                                 float* __restrict__ srz) {
    int k = blockIdx.x, tid = threadIdx.x;
    if (k == 0) srz[tid] = 0.f;  // sr0,sr1,sr2,mass (256 floats contiguous)
    float ss = 0.f;
    for (int i = tid; i < DIM; i += 256) { float v = centers[k * DIM + i]; ss += v * v; }
    __shared__ float red[4];
    for (int o = 32; o; o >>= 1) ss += __shfl_xor(ss, o);
    if ((tid & 63) == 0) red[tid >> 6] = ss;
    __syncthreads();
    ss = red[0] + red[1] + red[2] + red[3];
    float inv = 1.0f / fmaxf(sqrtf(ss), 1e-12f);
    for (int i = tid; i < DIM; i += 256) {
        float v = centers[k * DIM + i] * inv;
        cn[k * DIM + i] = v;
        cnbf[k * DIM + i] = f2bf(v);
    }
}

// ---------------- K1: logits GEMM (bf16 MFMA, K-split x2) + exp -> E, invn, sr0 ---
// Block: 32 rows, 4 waves. wave = (row-tile rt in {0,1}) x (K-half kh in {0,1}).
// kh==1 waves dump partial acc/ss to LDS; kh==0 waves merge and run the epilogue.
__global__ __launch_bounds__(256) void k_logits(const float* __restrict__ F,
                                                const short* __restrict__ cnbf,
                                                float* __restrict__ E,
                                                float* __restrict__ invn,
                                                float* __restrict__ sr0) {
    int tid = threadIdx.x;
    int wave = tid >> 6, lane = tid & 63;
    int rt = wave & 1, kh = wave >> 1;
    int l15 = lane & 15, lhi = lane >> 4;
    int rowbase = blockIdx.x * 32 + rt * 16;

    const float* Arow = F + (size_t)(rowbase + l15) * DIM + kh * 384 + lhi * 8;
    const short* Bbase = cnbf + (size_t)l15 * DIM + kh * 384 + lhi * 8;

    f32x4 acc[4];
#pragma unroll
    for (int n = 0; n < 4; ++n) acc[n] = (f32x4){0.f, 0.f, 0.f, 0.f};
    float ss = 0.f;

#pragma unroll
    for (int kb = 0; kb < 384; kb += 32) {
        float4 a0 = *(const float4*)(Arow + kb);
        float4 a1 = *(const float4*)(Arow + kb + 4);
        ss += a0.x * a0.x + a0.y * a0.y + a0.z * a0.z + a0.w * a0.w;
        ss += a1.x * a1.x + a1.y * a1.y + a1.z * a1.z + a1.w * a1.w;
        bf16x8 af;
        af[0] = f2bf(a0.x); af[1] = f2bf(a0.y); af[2] = f2bf(a0.z); af[3] = f2bf(a0.w);
        af[4] = f2bf(a1.x); af[5] = f2bf(a1.y); af[6] = f2bf(a1.z); af[7] = f2bf(a1.w);
#pragma unroll
        for (int n = 0; n < 4; ++n) {
            bf16x8 b = *(const bf16x8*)(Bbase + (size_t)n * 16 * DIM + kb);
            acc[n] = __builtin_amdgcn_mfma_f32_16x16x32_bf16(af, b, acc[n], 0, 0, 0);
        }
    }

    // merge K-halves through LDS
    __shared__ float mrg[2][64][16];  // [rt][lane][reg], 8 KiB (stride 16 -> 2-way, free)
    __shared__ float mss[2][64];
    if (kh == 1) {
#pragma unroll
        for (int n = 0; n < 4; ++n)
#pragma unroll
            for (int j = 0; j < 4; ++j) mrg[rt][lane][n * 4 + j] = acc[n][j];
        mss[rt][lane] = ss;
    }
    __syncthreads();

    float colp[4] = {0.f, 0.f, 0.f, 0.f};
    if (kh == 0) {
#pragma unroll
        for (int n = 0; n < 4; ++n)
#pragma unroll
            for (int j = 0; j < 4; ++j) acc[n][j] += mrg[rt][lane][n * 4 + j];
        ss += mss[rt][lane];

        ss += __shfl_xor(ss, 16);
        ss += __shfl_xor(ss, 32);
        float inv = 1.0f / fmaxf(sqrtf(ss), 1e-12f);
        if (lane < 16) invn[rowbase + lane] = inv;

        float sc[4];
#pragma unroll
        for (int j = 0; j < 4; ++j) sc[j] = __shfl(inv, lhi * 4 + j) * INV_T;

#pragma unroll
        for (int n = 0; n < 4; ++n) {
#pragma unroll
            for (int j = 0; j < 4; ++j) {
                float e = expf(acc[n][j] * sc[j]);
                E[(size_t)(rowbase + lhi * 4 + j) * KC + n * 16 + l15] = e;
                colp[n] += e;
            }
        }
#pragma unroll
        for (int n = 0; n < 4; ++n) {
            colp[n] += __shfl_xor(colp[n], 16);
            colp[n] += __shfl_xor(colp[n], 32);
        }
    }
    __shared__ float bsr[KC];
    if (tid < KC) bsr[tid] = 0.f;
    __syncthreads();
    if (kh == 0 && lane < 16) {
#pragma unroll
        for (int n = 0; n < 4; ++n) atomicAdd(&bsr[n * 16 + lane], colp[n]);
    }
    __syncthreads();
    if (tid < KC) atomicAdd(&sr0[tid], bsr[tid]);
}

// ---------------- P: fused R-chain + col-step + next row-step accumulation --------
template <int MODE>
__global__ __launch_bounds__(256) void k_sink(const float* __restrict__ E,
                                              const float* __restrict__ sr0,
                                              const float* __restrict__ sr1,
                                              const float* __restrict__ sr2,
                                              const float* __restrict__ invn,
                                              float* __restrict__ c,
                                              float* __restrict__ srNext,
                                              float* __restrict__ Aout,
                                              short* __restrict__ Qbf,
                                              float* __restrict__ mass) {
    int tid = threadIdx.x, lane = tid & 63;
    // R-chain (replica of the iteration scale math)
    float s0 = sr0[lane];
    float tot = s0;
    for (int o = 32; o; o >>= 1) tot += __shfl_xor(tot, o);
    float S = fmaxf(tot, 1e-12f);
    float Rl = (1.0f / S) / (fmaxf(s0 / S, 1e-12f) * 64.0f);
    if (MODE >= 1) Rl = Rl / (fmaxf(Rl * sr1[lane], 1e-12f) * 64.0f);
    if (MODE >= 2) Rl = Rl / (fmaxf(Rl * sr2[lane], 1e-12f) * 64.0f);

    int gw = blockIdx.x * 4 + (tid >> 6);
    float wacc = 0.f;
    int m0 = gw * 16;
    for (int i = 0; i < 16; i += 4) {  // 4-row ILP on the shuffle chains
        float e[4], v[4], s[4];
#pragma unroll
        for (int j = 0; j < 4; ++j) e[j] = E[(size_t)(m0 + i + j) * KC + lane];
#pragma unroll
        for (int j = 0; j < 4; ++j) { v[j] = e[j] * Rl; s[j] = v[j]; }
        for (int o = 32; o; o >>= 1) {
#pragma unroll
            for (int j = 0; j < 4; ++j) s[j] += __shfl_xor(s[j], o);
        }
#pragma unroll
        for (int j = 0; j < 4; ++j) {
            int m = m0 + i + j;
            float cold = (MODE == 0) ? 1.0f : c[m];
            float cnew = cold / (fmaxf(cold * s[j], 1e-12f) * 65536.0f);
            if (MODE == 2) {
                float a = v[j] * cnew * 65536.0f;
                size_t idx = (size_t)m * KC + lane;
                Aout[idx] = a;
                Qbf[idx] = f2bf(a * invn[m]);
                wacc += a;
            } else {
                if (lane == 0) c[m] = cnew;
                wacc += e[j] * cnew;
            }
        }
    }
    __shared__ float bacc[KC];
    if (tid < KC) bacc[tid] = 0.f;
    __syncthreads();
    atomicAdd(&bacc[lane], wacc);
    __syncthreads();
    if (tid < KC) atomicAdd((MODE == 2 ? mass : srNext) + tid, bacc[tid]);
}

// ---------------- K3: weighted centers — bf16 MFMA GEMM ---------------------------
// P[ms][k][d] = sum_{m in seg} Qbf[m][k] * bf16(F[m][d]). Block = 64k x 128d tile,
// 4 waves, LDS-staged transposed tiles ([k][m],[d][m]) with XOR swizzle (G4).
// F is read fp32 (L3-resident) and converted during the reg-stage transpose.
__global__ __launch_bounds__(256) void k_weighted(const float* __restrict__ F,
                                                  const short* __restrict__ Qbf,
                                                  float* __restrict__ P) {
    __shared__ short ldsF[DT * MB];  // [d][m] swizzled, 16 KiB
    __shared__ short ldsQ[KC * MB];  // [k][m] swizzled, 8 KiB
    int tid = threadIdx.x;
    int dt = blockIdx.x;  // 0..5
    int ms = blockIdx.y;  // 0..MSEG-1
    int wave = tid >> 6, lane = tid & 63;
    int l15 = lane & 15, lhi = lane >> 4;

    int m0 = ms * (MB * CH);
    int d0 = dt * DT;

    f32x4 acc[4][2];
#pragma unroll
    for (int kt = 0; kt < 4; ++kt)
#pragma unroll
        for (int ds = 0; ds < 2; ++ds) acc[kt][ds] = (f32x4){0.f, 0.f, 0.f, 0.f};

    // staging thread mappings
    int f_dq = (tid & 31) * 4;        // d 0..124 (float4 loads, 512B/row contiguous)
    int f_m8 = (tid >> 5) * 8;        // m 0..56
    int q_kq = (tid & 15) * 4;        // k 0..60   (threads <128)
    int q_m8 = ((tid >> 4) & 7) * 8;  // m 0..56

    for (int ch = 0; ch < CH; ++ch) {
        int mb = m0 + ch * MB;
        // ---- load F tile rows (fp32) ----
        float4 rf[8];
#pragma unroll
        for (int j = 0; j < 8; ++j)
            rf[j] = *(const float4*)(F + (size_t)(mb + f_m8 + j) * DIM + d0 + f_dq);
        // ---- load Q tile rows (bf16) ----
        u16x4 q[8];
        if (tid < 128) {
#pragma unroll
            for (int j = 0; j < 8; ++j)
                q[j] = *(const u16x4*)(Qbf + (size_t)(mb + q_m8 + j) * KC + q_kq);
        }
        __syncthreads();  // previous chunk's reads done before overwrite
#pragma unroll
        for (int i = 0; i < 4; ++i) {
            int d = f_dq + i;
            uint4 w;
            w.x = (unsigned)(unsigned short)f2bf(rf[0][i]) | ((unsigned)(unsigned short)f2bf(rf[1][i]) << 16);
            w.y = (unsigned)(unsigned short)f2bf(rf[2][i]) | ((unsigned)(unsigned short)f2bf(rf[3][i]) << 16);
            w.z = (unsigned)(unsigned short)f2bf(rf[4][i]) | ((unsigned)(unsigned short)f2bf(rf[5][i]) << 16);
            w.w = (unsigned)(unsigned short)f2bf(rf[6][i]) | ((unsigned)(unsigned short)f2bf(rf[7][i]) << 16);
            int byte = (d * (MB * 2) + f_m8 * 2) ^ ((d & 7) << 4);
            *(uint4*)((char*)ldsF + byte) = w;
        }
        if (tid < 128) {
#pragma unroll
            for (int i = 0; i < 4; ++i) {
                int k = q_kq + i;
                uint4 w;
                w.x = (unsigned)q[0][i] | ((unsigned)q[1][i] << 16);
                w.y = (unsigned)q[2][i] | ((unsigned)q[3][i] << 16);
                w.z = (unsigned)q[4][i] | ((unsigned)q[5][i] << 16);
                w.w = (unsigned)q[6][i] | ((unsigned)q[7][i] << 16);
                int byte = (k * (MB * 2) + q_m8 * 2) ^ ((k & 7) << 4);
                *(uint4*)((char*)ldsQ + byte) = w;
            }
        }
        __syncthreads();
        // ---- compute: 2 m-halves x 4 ktiles x 2 dsubs ----
#pragma unroll
        for (int h = 0; h < 2; ++h) {
            bf16x8 afr[4];
#pragma unroll
            for (int kt = 0; kt < 4; ++kt) {
                int k = kt * 16 + l15;
                int byte = (k * (MB * 2) + (h * 32 + lhi * 8) * 2) ^ ((k & 7) << 4);
                afr[kt] = *(bf16x8*)((char*)ldsQ + byte);
            }
#pragma unroll
            for (int ds = 0; ds < 2; ++ds) {
                int d = wave * 32 + ds * 16 + l15;
                int byte = (d * (MB * 2) + (h * 32 + lhi * 8) * 2) ^ ((d & 7) << 4);
                bf16x8 bfr = *(bf16x8*)((char*)ldsF + byte);
#pragma unroll
                for (int kt = 0; kt < 4; ++kt)
                    acc[kt][ds] = __builtin_amdgcn_mfma_f32_16x16x32_bf16(afr[kt], bfr, acc[kt][ds], 0, 0, 0);
            }
        }
        __syncthreads();
    }

    float* Pb = P + (size_t)ms * (KC * DIM) + d0;
#pragma unroll
    for (int kt = 0; kt < 4; ++kt)
#pragma unroll
        for (int ds = 0; ds < 2; ++ds) {
            int d = wave * 32 + ds * 16 + l15;
#pragma unroll
            for (int r4 = 0; r4 < 4; ++r4) {
                int k = kt * 16 + lhi * 4 + r4;
                Pb[(size_t)k * DIM + d] = acc[kt][ds][r4];
            }
        }
}

// ---------------- K4: reduce partials + finalize centers --------------------------
__global__ __launch_bounds__(256) void k_final(const float* __restrict__ P,
                                               const float* __restrict__ mass,
                                               const float* __restrict__ cn,
                                               float* __restrict__ outC) {
    int k = blockIdx.x, tid = threadIdx.x;
    float mk = fmaxf(mass[k], 1e-6f);
    float w[3];
#pragma unroll
    for (int g = 0; g < 3; ++g) {
        int d = tid + g * 256;
        float s0 = 0.f, s1 = 0.f, s2 = 0.f, s3 = 0.f;
        const float* p = P + (size_t)k * DIM + d;
#pragma unroll 4
        for (int msg = 0; msg < MSEG; msg += 4) {
            s0 += p[(size_t)msg * (KC * DIM)];
            s1 += p[(size_t)(msg + 1) * (KC * DIM)];
            s2 += p[(size_t)(msg + 2) * (KC * DIM)];
            s3 += p[(size_t)(msg + 3) * (KC * DIM)];
        }
        w[g] = ((s0 + s1) + (s2 + s3)) / mk;
    }
    float ss = w[0] * w[0] + w[1] * w[1] + w[2] * w[2];
    __shared__ float red[4];
    for (int o = 32; o; o >>= 1) ss += __shfl_xor(ss, o);
    if ((tid & 63) == 0) red[tid >> 6] = ss;
    __syncthreads();
    ss = red[0] + red[1] + red[2] + red[3];
    float n1 = fmaxf(sqrtf(ss), 1e-12f);

    float u0 = 0.99f * cn[k * DIM + tid]       + 0.01f * (w[0] / n1);
    float u1 = 0.99f * cn[k * DIM + tid + 256] + 0.01f * (w[1] / n1);
    float u2 = 0.99f * cn[k * DIM + tid + 512] + 0.01f * (w[2] / n1);
    float ss2 = u0 * u0 + u1 * u1 + u2 * u2;
    __syncthreads();
    for (int o = 32; o; o >>= 1) ss2 += __shfl_xor(ss2, o);
    if ((tid & 63) == 0) red[tid >> 6] = ss2;
    __syncthreads();
    ss2 = red[0] + red[1] + red[2] + red[3];
    float n2 = fmaxf(sqrtf(ss2), 1e-12f);

    outC[k * DIM + tid]       = u0 / n2;
    outC[k * DIM + tid + 256] = u1 / n2;
    outC[k * DIM + tid + 512] = u2 / n2;
}

extern "C" void kernel_launch(void* const* d_in, const int* in_sizes, int n_in,
                              void* d_out, int out_size, void* d_ws, size_t ws_size,
                              hipStream_t stream) {
    const float* F = (const float*)d_in[0];        // [65536][768]
    const float* centers = (const float*)d_in[1];  // [64][768]
    float* out = (float*)d_out;
    float* A = out;                                 // assignments [65536][64]
    float* outC = out + (size_t)M_TOTAL * KC;       // updated centers [64][768]

    float* w = (float*)d_ws;                        // ws = 768 MiB (poison fill evidence)
    float* cn   = w;                                // 49152
    short* cnbf = (short*)(w + 49152);              // 24576 float slots
    float* sr0  = w + 73728;                        // sr0,sr1,sr2,mass: 256 floats
    float* sr1  = sr0 + 64;
    float* sr2  = sr0 + 128;
    float* mass = sr0 + 192;
    float* invn = w + 73984;                        // 65536
    float* cbuf = w + 139520;                       // 65536
    float* E    = w + 205056;                       // 4194304
    short* Qbf  = (short*)(w + 4399360);            // 4194304 shorts (8 MiB)
    float* partial = w + 6496512;                   // MSEG*64*768 = 3145728 (12 MiB)

    k_centers<<<KC, 256, 0, stream>>>(centers, cn, cnbf, sr0);
    k_logits<<<M_TOTAL / 32, 256, 0, stream>>>(F, cnbf, E, invn, sr0);
    k_sink<0><<<1024, 256, 0, stream>>>(E, sr0, sr1, sr2, invn, cbuf, sr1, A, Qbf, mass);
    k_sink<1><<<1024, 256, 0, stream>>>(E, sr0, sr1, sr2, invn, cbuf, sr2, A, Qbf, mass);
    k_sink<2><<<1024, 256, 0, stream>>>(E, sr0, sr1, sr2, invn, cbuf, nullptr, A, Qbf, mass);

    dim3 wgrid(DIM / DT, MSEG);
    k_weighted<<<wgrid, 256, 0, stream>>>(F, Qbf, partial);
    k_final<<<KC, 256, 0, stream>>>(partial, mass, cn, outC);
}

// Round 5
// 224.555 us; speedup vs baseline: 1.9211x; 1.0315x over previous
//
#include <hip/hip_runtime.h>
#include <hip/hip_bf16.h>

#define M_TOTAL 65536
#define DIM 768
#define KC 64
#define INV_T 10.0f

// k_weighted tiling
#define DT 128    // d-cols per block
#define MB 64     // m per LDS chunk
#define CH 8      // chunks per block (m-range 512)
#define MSEG 128  // m-segments (partials)

#define LOGITS_BLOCKS (M_TOTAL / 32)   // 2048
#define SINK_BLOCKS 1024

typedef __attribute__((ext_vector_type(4))) float f32x4;
typedef __attribute__((ext_vector_type(8))) short bf16x8;
typedef __attribute__((ext_vector_type(4))) unsigned short u16x4;

__device__ __forceinline__ short f2bf(float f) {
    __hip_bfloat16 h = __float2bfloat16(f);
    union { __hip_bfloat16 h; short s; } u; u.h = h;
    return u.s;
}

// ---------------- K0: normalize centers -> cn (fp32) + cnbf (bf16) ----------------
__global__ __launch_bounds__(256) void k_centers(const float* __restrict__ centers,
                                                 float* __restrict__ cn,
                                                 short* __restrict__ cnbf) {
    int k = blockIdx.x, tid = threadIdx.x;
    float ss = 0.f;
    for (int i = tid; i < DIM; i += 256) { float v = centers[k * DIM + i]; ss += v * v; }
    __shared__ float red[4];
    for (int o = 32; o; o >>= 1) ss += __shfl_xor(ss, o);
    if ((tid & 63) == 0) red[tid >> 6] = ss;
    __syncthreads();
    ss = red[0] + red[1] + red[2] + red[3];
    float inv = 1.0f / fmaxf(sqrtf(ss), 1e-12f);
    for (int i = tid; i < DIM; i += 256) {
        float v = centers[k * DIM + i] * inv;
        cn[k * DIM + i] = v;
        cnbf[k * DIM + i] = f2bf(v);
    }
}

// ---------------- K1: logits GEMM (bf16 MFMA, K-split x2) + exp -> E, invn, PS0 ---
// Block: 32 rows, 4 waves = (row-tile rt) x (K-half kh). Balanced epilogue:
// kh0 handles n-tiles 0,1; kh1 handles 2,3 (accs cross-exchanged through LDS).
// Block col-sums written as per-block partial row PS0[blk][64] (no atomics).
__global__ __launch_bounds__(256) void k_logits(const float* __restrict__ F,
                                                const short* __restrict__ cnbf,
                                                float* __restrict__ E,
                                                float* __restrict__ invn,
                                                float* __restrict__ PS0) {
    int tid = threadIdx.x;
    int wave = tid >> 6, lane = tid & 63;
    int rt = wave & 1, kh = wave >> 1;
    int l15 = lane & 15, lhi = lane >> 4;
    int rowbase = blockIdx.x * 32 + rt * 16;

    const float* Arow = F + (size_t)(rowbase + l15) * DIM + kh * 384 + lhi * 8;
    const short* Bbase = cnbf + (size_t)l15 * DIM + kh * 384 + lhi * 8;

    f32x4 acc[4];
#pragma unroll
    for (int n = 0; n < 4; ++n) acc[n] = (f32x4){0.f, 0.f, 0.f, 0.f};
    float ss = 0.f;

#pragma unroll
    for (int kb = 0; kb < 384; kb += 32) {
        float4 a0 = *(const float4*)(Arow + kb);
        float4 a1 = *(const float4*)(Arow + kb + 4);
        ss += a0.x * a0.x + a0.y * a0.y + a0.z * a0.z + a0.w * a0.w;
        ss += a1.x * a1.x + a1.y * a1.y + a1.z * a1.z + a1.w * a1.w;
        bf16x8 af;
        af[0] = f2bf(a0.x); af[1] = f2bf(a0.y); af[2] = f2bf(a0.z); af[3] = f2bf(a0.w);
        af[4] = f2bf(a1.x); af[5] = f2bf(a1.y); af[6] = f2bf(a1.z); af[7] = f2bf(a1.w);
#pragma unroll
        for (int n = 0; n < 4; ++n) {
            bf16x8 b = *(const bf16x8*)(Bbase + (size_t)n * 16 * DIM + kb);
            acc[n] = __builtin_amdgcn_mfma_f32_16x16x32_bf16(af, b, acc[n], 0, 0, 0);
        }
    }

    // cross-exchange: kh0 gives its n=2,3 halves; kh1 gives its n=0,1 halves + ss
    __shared__ float mrgA[2][64][8];  // kh0 -> acc[2],acc[3]
    __shared__ float mrgB[2][64][8];  // kh1 -> acc[0],acc[1]
    __shared__ float mssB[2][64];
    __shared__ float minv[2][16];
    __shared__ float bsr[2][64];
    if (kh == 0) {
#pragma unroll
        for (int j = 0; j < 4; ++j) { mrgA[rt][lane][j] = acc[2][j]; mrgA[rt][lane][4 + j] = acc[3][j]; }
    } else {
#pragma unroll
        for (int j = 0; j < 4; ++j) { mrgB[rt][lane][j] = acc[0][j]; mrgB[rt][lane][4 + j] = acc[1][j]; }
        mssB[rt][lane] = ss;
    }
    __syncthreads();

    if (kh == 0) {
#pragma unroll
        for (int j = 0; j < 4; ++j) { acc[0][j] += mrgB[rt][lane][j]; acc[1][j] += mrgB[rt][lane][4 + j]; }
        ss += mssB[rt][lane];
        ss += __shfl_xor(ss, 16);
        ss += __shfl_xor(ss, 32);
        float inv = 1.0f / fmaxf(sqrtf(ss), 1e-12f);
        if (lane < 16) { invn[rowbase + lane] = inv; minv[rt][lane] = inv; }
    } else {
#pragma unroll
        for (int j = 0; j < 4; ++j) { acc[2][j] += mrgA[rt][lane][j]; acc[3][j] += mrgA[rt][lane][4 + j]; }
    }
    __syncthreads();

    float sc[4];
#pragma unroll
    for (int j = 0; j < 4; ++j) sc[j] = minv[rt][lhi * 4 + j] * INV_T;

    float colp[2] = {0.f, 0.f};
#pragma unroll
    for (int nn = 0; nn < 2; ++nn) {
        int n = kh * 2 + nn;
#pragma unroll
        for (int j = 0; j < 4; ++j) {
            float e = expf(acc[n][j] * sc[j]);
            E[(size_t)(rowbase + lhi * 4 + j) * KC + n * 16 + l15] = e;
            colp[nn] += e;
        }
    }
#pragma unroll
    for (int nn = 0; nn < 2; ++nn) {
        colp[nn] += __shfl_xor(colp[nn], 16);
        colp[nn] += __shfl_xor(colp[nn], 32);
    }
    if (lane < 16) {
#pragma unroll
        for (int nn = 0; nn < 2; ++nn) bsr[rt][(kh * 2 + nn) * 16 + lane] = colp[nn];
    }
    __syncthreads();
    if (tid < KC) PS0[(size_t)blockIdx.x * KC + tid] = bsr[0][tid] + bsr[1][tid];
}

// ---------------- k_redR: reduce per-block partials + compute R scale -------------
// STAGE 0: R = (1/S)/(max(sk/S)*K)   (global-sum + first row step)
// STAGE 1+: R = Rin/(max(Rin*sk)*K)  (subsequent row steps)
template <int STAGE>
__global__ __launch_bounds__(1024) void k_redR(const float* __restrict__ PS, int nblocks,
                                               const float* __restrict__ Rin,
                                               float* __restrict__ Rout) {
    __shared__ float part[16][KC];
    int k = threadIdx.x & 63, g = threadIdx.x >> 6;
    float s = 0.f;
    for (int p = g; p < nblocks; p += 16) s += PS[(size_t)p * KC + k];
    part[g][k] = s;
    __syncthreads();
    if (threadIdx.x < KC) {
        float sk = 0.f;
#pragma unroll
        for (int g2 = 0; g2 < 16; ++g2) sk += part[g2][k];
        if (STAGE == 0) {
            float tot = sk;
            for (int o = 32; o; o >>= 1) tot += __shfl_xor(tot, o);
            float S = fmaxf(tot, 1e-12f);
            Rout[k] = (1.0f / S) / (fmaxf(sk / S, 1e-12f) * 64.0f);
        } else {
            float r = Rin[k];
            Rout[k] = r / (fmaxf(r * sk, 1e-12f) * 64.0f);
        }
    }
}

// ---------------- P: col-step + next row-step partial accumulation ----------------
// MODE 0: c_old = 1, writes c;  MODE 1: updates c;  MODE 2: writes A, Qbf, mass-partials.
template <int MODE>
__global__ __launch_bounds__(256) void k_sink(const float* __restrict__ E,
                                              const float* __restrict__ R,
                                              const float* __restrict__ invn,
                                              float* __restrict__ c,
                                              float* __restrict__ PS,
                                              float* __restrict__ Aout,
                                              short* __restrict__ Qbf) {
    int tid = threadIdx.x, lane = tid & 63, wave = tid >> 6;
    float Rl = R[lane];
    int gw = blockIdx.x * 4 + wave;
    float wacc = 0.f;
    int m0 = gw * 16;
    for (int i = 0; i < 16; i += 4) {  // 4-row ILP on the shuffle chains
        float e[4], v[4], s[4];
#pragma unroll
        for (int j = 0; j < 4; ++j) e[j] = E[(size_t)(m0 + i + j) * KC + lane];
#pragma unroll
        for (int j = 0; j < 4; ++j) { v[j] = e[j] * Rl; s[j] = v[j]; }
        for (int o = 32; o; o >>= 1) {
#pragma unroll
            for (int j = 0; j < 4; ++j) s[j] += __shfl_xor(s[j], o);
        }
#pragma unroll
        for (int j = 0; j < 4; ++j) {
            int m = m0 + i + j;
            float cold = (MODE == 0) ? 1.0f : c[m];
            float cnew = cold / (fmaxf(cold * s[j], 1e-12f) * 65536.0f);
            if (MODE == 2) {
                float a = v[j] * cnew * 65536.0f;
                size_t idx = (size_t)m * KC + lane;
                Aout[idx] = a;
                Qbf[idx] = f2bf(a * invn[m]);
                wacc += a;
            } else {
                if (lane == 0) c[m] = cnew;
                wacc += e[j] * cnew;
            }
        }
    }
    __shared__ float bacc[4][KC];
    bacc[wave][lane] = wacc;
    __syncthreads();
    if (tid < KC) PS[(size_t)blockIdx.x * KC + tid] =
        bacc[0][tid] + bacc[1][tid] + bacc[2][tid] + bacc[3][tid];
}

// ---------------- K3: weighted centers — bf16 MFMA GEMM, prefetched ---------------
// P[ms][k][d] = sum_{m in seg} Qbf[m][k] * bf16(F[m][d]). Block = 64k x 128d tile,
// 4 waves; LDS transposed tiles with XOR swizzle; chunk ch+1 global loads issued
// before chunk ch's MFMA so HBM latency hides under compute (T14).
__global__ __launch_bounds__(256) void k_weighted(const float* __restrict__ F,
                                                  const short* __restrict__ Qbf,
                                                  float* __restrict__ P) {
    __shared__ short ldsF[DT * MB];  // [d][m] swizzled, 16 KiB
    __shared__ short ldsQ[KC * MB];  // [k][m] swizzled, 8 KiB
    int tid = threadIdx.x;
    int dt = blockIdx.x;  // 0..5
    int ms = blockIdx.y;  // 0..MSEG-1
    int wave = tid >> 6, lane = tid & 63;
    int l15 = lane & 15, lhi = lane >> 4;

    int m0 = ms * (MB * CH);
    int d0 = dt * DT;

    f32x4 acc[4][2];
#pragma unroll
    for (int kt = 0; kt < 4; ++kt)
#pragma unroll
        for (int ds = 0; ds < 2; ++ds) acc[kt][ds] = (f32x4){0.f, 0.f, 0.f, 0.f};

    int f_dq = (tid & 31) * 4;        // d 0..124 (float4 loads)
    int f_m8 = (tid >> 5) * 8;        // m 0..56
    int q_kq = (tid & 15) * 4;        // k 0..60   (threads <128)
    int q_m8 = ((tid >> 4) & 7) * 8;  // m 0..56

    float4 rf[8];
    u16x4 q[8];
#define LOADCH(mb_)                                                                       \
    do {                                                                                  \
        _Pragma("unroll") for (int j = 0; j < 8; ++j)                                     \
            rf[j] = *(const float4*)(F + (size_t)((mb_) + f_m8 + j) * DIM + d0 + f_dq);   \
        if (tid < 128) {                                                                  \
            _Pragma("unroll") for (int j = 0; j < 8; ++j)                                 \
                q[j] = *(const u16x4*)(Qbf + (size_t)((mb_) + q_m8 + j) * KC + q_kq);     \
        }                                                                                 \
    } while (0)

    LOADCH(m0);
    for (int ch = 0; ch < CH; ++ch) {
        __syncthreads();  // previous chunk's LDS reads done before overwrite
#pragma unroll
        for (int i = 0; i < 4; ++i) {
            int d = f_dq + i;
            uint4 w;
            w.x = (unsigned)(unsigned short)f2bf(rf[0][i]) | ((unsigned)(unsigned short)f2bf(rf[1][i]) << 16);
            w.y = (unsigned)(unsigned short)f2bf(rf[2][i]) | ((unsigned)(unsigned short)f2bf(rf[3][i]) << 16);
            w.z = (unsigned)(unsigned short)f2bf(rf[4][i]) | ((unsigned)(unsigned short)f2bf(rf[5][i]) << 16);
            w.w = (unsigned)(unsigned short)f2bf(rf[6][i]) | ((unsigned)(unsigned short)f2bf(rf[7][i]) << 16);
            int byte = (d * (MB * 2) + f_m8 * 2) ^ ((d & 7) << 4);
            *(uint4*)((char*)ldsF + byte) = w;
        }
        if (tid < 128) {
#pragma unroll
            for (int i = 0; i < 4; ++i) {
                int k = q_kq + i;
                uint4 w;
                w.x = (unsigned)q[0][i] | ((unsigned)q[1][i] << 16);
                w.y = (unsigned)q[2][i] | ((unsigned)q[3][i] << 16);
                w.z = (unsigned)q[4][i] | ((unsigned)q[5][i] << 16);
                w.w = (unsigned)q[6][i] | ((unsigned)q[7][i] << 16);
                int byte = (k * (MB * 2) + q_m8 * 2) ^ ((k & 7) << 4);
                *(uint4*)((char*)ldsQ + byte) = w;
            }
        }
        __syncthreads();
        if (ch + 1 < CH) LOADCH(m0 + (ch + 1) * MB);  // prefetch overlaps MFMA below
#pragma unroll
        for (int h = 0; h < 2; ++h) {
            bf16x8 afr[4];
#pragma unroll
            for (int kt = 0; kt < 4; ++kt) {
                int k = kt * 16 + l15;
                int byte = (k * (MB * 2) + (h * 32 + lhi * 8) * 2) ^ ((k & 7) << 4);
                afr[kt] = *(bf16x8*)((char*)ldsQ + byte);
            }
#pragma unroll
            for (int ds = 0; ds < 2; ++ds) {
                int d = wave * 32 + ds * 16 + l15;
                int byte = (d * (MB * 2) + (h * 32 + lhi * 8) * 2) ^ ((d & 7) << 4);
                bf16x8 bfr = *(bf16x8*)((char*)ldsF + byte);
#pragma unroll
                for (int kt = 0; kt < 4; ++kt)
                    acc[kt][ds] = __builtin_amdgcn_mfma_f32_16x16x32_bf16(afr[kt], bfr, acc[kt][ds], 0, 0, 0);
            }
        }
    }
#undef LOADCH

    float* Pb = P + (size_t)ms * (KC * DIM) + d0;
#pragma unroll
    for (int kt = 0; kt < 4; ++kt)
#pragma unroll
        for (int ds = 0; ds < 2; ++ds) {
            int d = wave * 32 + ds * 16 + l15;
#pragma unroll
            for (int r4 = 0; r4 < 4; ++r4) {
                int k = kt * 16 + lhi * 4 + r4;
                Pb[(size_t)k * DIM + d] = acc[kt][ds][r4];
            }
        }
}

// ---------------- R2: reduce the MSEG partials -> weighted ------------------------
__global__ __launch_bounds__(128) void k_reducep(const float* __restrict__ P,
                                                 float* __restrict__ W) {
    int o = blockIdx.x * 128 + threadIdx.x;  // 0..49151
    const float* p = P + o;
    float s0 = 0.f, s1 = 0.f, s2 = 0.f, s3 = 0.f;
    size_t stride = (size_t)KC * DIM;
#pragma unroll 4
    for (int g = 0; g < MSEG; g += 4) {
        s0 += p[(size_t)g * stride];
        s1 += p[(size_t)(g + 1) * stride];
        s2 += p[(size_t)(g + 2) * stride];
        s3 += p[(size_t)(g + 3) * stride];
    }
    W[o] = (s0 + s1) + (s2 + s3);
}

// ---------------- K4: mass-reduce + finalize centers ------------------------------
__global__ __launch_bounds__(256) void k_final(const float* __restrict__ W,
                                               const float* __restrict__ PSM,
                                               const float* __restrict__ cn,
                                               float* __restrict__ outC) {
    int k = blockIdx.x, tid = threadIdx.x;
    __shared__ float red[4];

    // mass[k] = sum over SINK_BLOCKS partials
    float msum = 0.f;
    for (int p = tid; p < SINK_BLOCKS; p += 256) msum += PSM[(size_t)p * KC + k];
    for (int o = 32; o; o >>= 1) msum += __shfl_xor(msum, o);
    if ((tid & 63) == 0) red[tid >> 6] = msum;
    __syncthreads();
    float mk = fmaxf(red[0] + red[1] + red[2] + red[3], 1e-6f);
    __syncthreads();

    float w[3];
#pragma unroll
    for (int g = 0; g < 3; ++g) w[g] = W[k * DIM + tid + g * 256] / mk;

    float ss = w[0] * w[0] + w[1] * w[1] + w[2] * w[2];
    for (int o = 32; o; o >>= 1) ss += __shfl_xor(ss, o);
    if ((tid & 63) == 0) red[tid >> 6] = ss;
    __syncthreads();
    ss = red[0] + red[1] + red[2] + red[3];
    float n1 = fmaxf(sqrtf(ss), 1e-12f);
    __syncthreads();

    float u0 = 0.99f * cn[k * DIM + tid]       + 0.01f * (w[0] / n1);
    float u1 = 0.99f * cn[k * DIM + tid + 256] + 0.01f * (w[1] / n1);
    float u2 = 0.99f * cn[k * DIM + tid + 512] + 0.01f * (w[2] / n1);
    float ss2 = u0 * u0 + u1 * u1 + u2 * u2;
    for (int o = 32; o; o >>= 1) ss2 += __shfl_xor(ss2, o);
    if ((tid & 63) == 0) red[tid >> 6] = ss2;
    __syncthreads();
    ss2 = red[0] + red[1] + red[2] + red[3];
    float n2 = fmaxf(sqrtf(ss2), 1e-12f);

    outC[k * DIM + tid]       = u0 / n2;
    outC[k * DIM + tid + 256] = u1 / n2;
    outC[k * DIM + tid + 512] = u2 / n2;
}

extern "C" void kernel_launch(void* const* d_in, const int* in_sizes, int n_in,
                              void* d_out, int out_size, void* d_ws, size_t ws_size,
                              hipStream_t stream) {
    const float* F = (const float*)d_in[0];        // [65536][768]
    const float* centers = (const float*)d_in[1];  // [64][768]
    float* out = (float*)d_out;
    float* A = out;                                 // assignments [65536][64]
    float* outC = out + (size_t)M_TOTAL * KC;       // updated centers [64][768]

    float* w = (float*)d_ws;                        // ws = 768 MiB
    float* cn   = w;                                // 49152
    short* cnbf = (short*)(w + 49152);              // 24576 float slots
    float* R0   = w + 73728;                        // 64
    float* R1   = R0 + 64;
    float* R2   = R0 + 128;
    float* invn = w + 73984;                        // 65536
    float* cbuf = w + 139520;                       // 65536
    float* E    = w + 205056;                       // 4194304
    short* Qbf  = (short*)(w + 4399360);            // 2097152 float slots (8 MiB)
    float* PS0  = w + 6496512;                      // 2048*64 = 131072
    float* PS1  = w + 6627584;                      // 1024*64 = 65536
    float* PS2  = w + 6693120;                      // 65536
    float* PSM  = w + 6758656;                      // 65536
    float* partial = w + 6824192;                   // MSEG*64*768 = 6291456 (24 MiB)
    float* weighted = w + 13115648;                 // 49152

    k_centers<<<KC, 256, 0, stream>>>(centers, cn, cnbf);
    k_logits<<<LOGITS_BLOCKS, 256, 0, stream>>>(F, cnbf, E, invn, PS0);
    k_redR<0><<<1, 1024, 0, stream>>>(PS0, LOGITS_BLOCKS, nullptr, R0);
    k_sink<0><<<SINK_BLOCKS, 256, 0, stream>>>(E, R0, invn, cbuf, PS1, A, Qbf);
    k_redR<1><<<1, 1024, 0, stream>>>(PS1, SINK_BLOCKS, R0, R1);
    k_sink<1><<<SINK_BLOCKS, 256, 0, stream>>>(E, R1, invn, cbuf, PS2, A, Qbf);
    k_redR<1><<<1, 1024, 0, stream>>>(PS2, SINK_BLOCKS, R1, R2);
    k_sink<2><<<SINK_BLOCKS, 256, 0, stream>>>(E, R2, invn, cbuf, PSM, A, Qbf);

    dim3 wgrid(DIM / DT, MSEG);
    k_weighted<<<wgrid, 256, 0, stream>>>(F, Qbf, partial);
    k_reducep<<<(KC * DIM) / 128, 128, 0, stream>>>(partial, weighted);
    k_final<<<KC, 256, 0, stream>>>(weighted, PSM, cn, outC);
}

// Round 6
// 207.087 us; speedup vs baseline: 2.0831x; 1.0844x over previous
//
#include <hip/hip_runtime.h>
#include <hip/hip_bf16.h>

#define M_TOTAL 65536
#define DIM 768
#define KC 64
#define INV_T 10.0f

// k_weighted tiling
#define DT 128    // d-cols per block
#define MB 64     // m per LDS chunk
#define CH 8      // chunks per block (m-range 512)
#define MSEG 128  // m-segments (partials)

#define LOGITS_BLOCKS (M_TOTAL / 64)   // 1024 (64 rows per block)
#define SINK_BLOCKS 1024

typedef __attribute__((ext_vector_type(4))) float f32x4;
typedef __attribute__((ext_vector_type(8))) short bf16x8;
typedef __attribute__((ext_vector_type(4))) unsigned short u16x4;

__device__ __forceinline__ short f2bf(float f) {
    __hip_bfloat16 h = __float2bfloat16(f);
    union { __hip_bfloat16 h; short s; } u; u.h = h;
    return u.s;
}

// ---------------- K0: normalize centers -> cn (fp32) + cnbf (bf16) ----------------
__global__ __launch_bounds__(256) void k_centers(const float* __restrict__ centers,
                                                 float* __restrict__ cn,
                                                 short* __restrict__ cnbf) {
    int k = blockIdx.x, tid = threadIdx.x;
    float ss = 0.f;
    for (int i = tid; i < DIM; i += 256) { float v = centers[k * DIM + i]; ss += v * v; }
    __shared__ float red[4];
    for (int o = 32; o; o >>= 1) ss += __shfl_xor(ss, o);
    if ((tid & 63) == 0) red[tid >> 6] = ss;
    __syncthreads();
    ss = red[0] + red[1] + red[2] + red[3];
    float inv = 1.0f / fmaxf(sqrtf(ss), 1e-12f);
    for (int i = tid; i < DIM; i += 256) {
        float v = centers[k * DIM + i] * inv;
        cn[k * DIM + i] = v;
        cnbf[k * DIM + i] = f2bf(v);
    }
}

// ---------------- K1: logits GEMM, global_load_lds 2-phase staged -----------------
// Block: 64 rows, 4 waves (wave = 16-row tile). K tiled 12 x 64 f32, double-buffered
// LDS (2 x 16 KiB). Staging: linear LDS dest (HW requirement) + XOR-swizzled global
// SOURCE col (c ^= (row&7)<<2); ds_read applies the same involution (rule #21).
__global__ __launch_bounds__(256) void k_logits(const float* __restrict__ F,
                                                const short* __restrict__ cnbf,
                                                float* __restrict__ E,
                                                float* __restrict__ invn,
                                                float* __restrict__ PS0) {
    __shared__ float fbuf[2][4096];  // [row 0..63][col 0..63], swizzled-by-source
    __shared__ float bsr[4][KC];
    int tid = threadIdx.x;
    int wave = tid >> 6, lane = tid & 63;
    int l15 = lane & 15, lhi = lane >> 4;
    int rowbase = blockIdx.x * 64;

    int srow = tid >> 4;       // staging row 0..15 (+16 per issue)
    int c4 = (tid & 15) * 4;   // staging col group

    f32x4 acc[4];
#pragma unroll
    for (int n = 0; n < 4; ++n) acc[n] = (f32x4){0.f, 0.f, 0.f, 0.f};
    float ss = 0.f;

    auto stage = [&](int t, int b) {
#pragma unroll
        for (int i = 0; i < 4; ++i) {
            int row = i * 16 + srow;
            const float* src = F + (size_t)(rowbase + row) * DIM + t * 64 + (c4 ^ ((row & 7) << 2));
            float* dst = &fbuf[b][i * 1024 + wave * 256];  // wave-uniform; HW adds lane*16B
            __builtin_amdgcn_global_load_lds((const __attribute__((address_space(1))) void*)src,
                                             (__attribute__((address_space(3))) void*)dst, 16, 0, 0);
        }
    };

    stage(0, 0);
    __syncthreads();

    int myrow = wave * 16 + l15;
    int swz = (l15 & 7) << 2;
    const short* Bb = cnbf + (size_t)l15 * DIM + lhi * 8;

    for (int t = 0; t < 12; ++t) {
        int cur = t & 1;
        if (t < 11) stage(t + 1, cur ^ 1);  // in flight during compute below
        const float* cb = fbuf[cur] + myrow * 64;
#pragma unroll
        for (int kk = 0; kk < 64; kk += 32) {
            int c0s = (kk + lhi * 8) ^ swz;
            f32x4 fa = *(const f32x4*)(cb + c0s);
            f32x4 fb2 = *(const f32x4*)(cb + (c0s ^ 4));
            ss += fa[0] * fa[0] + fa[1] * fa[1] + fa[2] * fa[2] + fa[3] * fa[3]
                + fb2[0] * fb2[0] + fb2[1] * fb2[1] + fb2[2] * fb2[2] + fb2[3] * fb2[3];
            bf16x8 af;
            af[0] = f2bf(fa[0]); af[1] = f2bf(fa[1]); af[2] = f2bf(fa[2]); af[3] = f2bf(fa[3]);
            af[4] = f2bf(fb2[0]); af[5] = f2bf(fb2[1]); af[6] = f2bf(fb2[2]); af[7] = f2bf(fb2[3]);
#pragma unroll
            for (int n = 0; n < 4; ++n) {
                bf16x8 b = *(const bf16x8*)(Bb + (size_t)n * 16 * DIM + t * 64 + kk);
                acc[n] = __builtin_amdgcn_mfma_f32_16x16x32_bf16(af, b, acc[n], 0, 0, 0);
            }
        }
        __syncthreads();  // drains next-tile staging (vmcnt 0) + LDS reads done
    }

    // ---- per-wave epilogue: rows rowbase + wave*16 + * ----
    ss += __shfl_xor(ss, 16);
    ss += __shfl_xor(ss, 32);
    float inv = 1.0f / fmaxf(sqrtf(ss), 1e-12f);
    int growbase = rowbase + wave * 16;
    if (lane < 16) invn[growbase + lane] = inv;

    float sc[4];
#pragma unroll
    for (int j = 0; j < 4; ++j) sc[j] = __shfl(inv, lhi * 4 + j) * INV_T;

    float colp[4] = {0.f, 0.f, 0.f, 0.f};
#pragma unroll
    for (int n = 0; n < 4; ++n) {
#pragma unroll
        for (int j = 0; j < 4; ++j) {
            float e = expf(acc[n][j] * sc[j]);
            E[(size_t)(growbase + lhi * 4 + j) * KC + n * 16 + l15] = e;
            colp[n] += e;
        }
    }
#pragma unroll
    for (int n = 0; n < 4; ++n) {
        colp[n] += __shfl_xor(colp[n], 16);
        colp[n] += __shfl_xor(colp[n], 32);
    }
    if (lane < 16) {
#pragma unroll
        for (int n = 0; n < 4; ++n) bsr[wave][n * 16 + lane] = colp[n];
    }
    __syncthreads();
    if (tid < KC) PS0[(size_t)blockIdx.x * KC + tid] =
        bsr[0][tid] + bsr[1][tid] + bsr[2][tid] + bsr[3][tid];
}

// ---------------- k_redR: reduce per-block partials + compute R scale -------------
template <int STAGE>
__global__ __launch_bounds__(1024) void k_redR(const float* __restrict__ PS, int nblocks,
                                               const float* __restrict__ Rin,
                                               float* __restrict__ Rout) {
    __shared__ float part[16][KC];
    int k = threadIdx.x & 63, g = threadIdx.x >> 6;
    float s = 0.f;
    for (int p = g; p < nblocks; p += 16) s += PS[(size_t)p * KC + k];
    part[g][k] = s;
    __syncthreads();
    if (threadIdx.x < KC) {
        float sk = 0.f;
#pragma unroll
        for (int g2 = 0; g2 < 16; ++g2) sk += part[g2][k];
        if (STAGE == 0) {
            float tot = sk;
            for (int o = 32; o; o >>= 1) tot += __shfl_xor(tot, o);
            float S = fmaxf(tot, 1e-12f);
            Rout[k] = (1.0f / S) / (fmaxf(sk / S, 1e-12f) * 64.0f);
        } else {
            float r = Rin[k];
            Rout[k] = r / (fmaxf(r * sk, 1e-12f) * 64.0f);
        }
    }
}

// ---------------- P: col-step + next row-step partial accumulation ----------------
template <int MODE>
__global__ __launch_bounds__(256) void k_sink(const float* __restrict__ E,
                                              const float* __restrict__ R,
                                              const float* __restrict__ invn,
                                              float* __restrict__ c,
                                              float* __restrict__ PS,
                                              float* __restrict__ Aout,
                                              short* __restrict__ Qbf) {
    int tid = threadIdx.x, lane = tid & 63, wave = tid >> 6;
    float Rl = R[lane];
    int gw = blockIdx.x * 4 + wave;
    float wacc = 0.f;
    int m0 = gw * 16;
    for (int i = 0; i < 16; i += 4) {  // 4-row ILP on the shuffle chains
        float e[4], v[4], s[4];
#pragma unroll
        for (int j = 0; j < 4; ++j) e[j] = E[(size_t)(m0 + i + j) * KC + lane];
#pragma unroll
        for (int j = 0; j < 4; ++j) { v[j] = e[j] * Rl; s[j] = v[j]; }
        for (int o = 32; o; o >>= 1) {
#pragma unroll
            for (int j = 0; j < 4; ++j) s[j] += __shfl_xor(s[j], o);
        }
#pragma unroll
        for (int j = 0; j < 4; ++j) {
            int m = m0 + i + j;
            float cold = (MODE == 0) ? 1.0f : c[m];
            float cnew = cold / (fmaxf(cold * s[j], 1e-12f) * 65536.0f);
            if (MODE == 2) {
                float a = v[j] * cnew * 65536.0f;
                size_t idx = (size_t)m * KC + lane;
                Aout[idx] = a;
                Qbf[idx] = f2bf(a * invn[m]);
                wacc += a;
            } else {
                if (lane == 0) c[m] = cnew;
                wacc += e[j] * cnew;
            }
        }
    }
    __shared__ float bacc[4][KC];
    bacc[wave][lane] = wacc;
    __syncthreads();
    if (tid < KC) PS[(size_t)blockIdx.x * KC + tid] =
        bacc[0][tid] + bacc[1][tid] + bacc[2][tid] + bacc[3][tid];
}

// ---------------- K3: weighted centers — bf16 MFMA GEMM, prefetched ---------------
__global__ __launch_bounds__(256) void k_weighted(const float* __restrict__ F,
                                                  const short* __restrict__ Qbf,
                                                  float* __restrict__ P) {
    __shared__ short ldsF[DT * MB];  // [d][m] swizzled, 16 KiB
    __shared__ short ldsQ[KC * MB];  // [k][m] swizzled, 8 KiB
    int tid = threadIdx.x;
    int dt = blockIdx.x;  // 0..5
    int ms = blockIdx.y;  // 0..MSEG-1
    int wave = tid >> 6, lane = tid & 63;
    int l15 = lane & 15, lhi = lane >> 4;

    int m0 = ms * (MB * CH);
    int d0 = dt * DT;

    f32x4 acc[4][2];
#pragma unroll
    for (int kt = 0; kt < 4; ++kt)
#pragma unroll
        for (int ds = 0; ds < 2; ++ds) acc[kt][ds] = (f32x4){0.f, 0.f, 0.f, 0.f};

    int f_dq = (tid & 31) * 4;        // d 0..124 (float4 loads)
    int f_m8 = (tid >> 5) * 8;        // m 0..56
    int q_kq = (tid & 15) * 4;        // k 0..60   (threads <128)
    int q_m8 = ((tid >> 4) & 7) * 8;  // m 0..56

    float4 rf[8];
    u16x4 q[8];
#define LOADCH(mb_)                                                                       \
    do {                                                                                  \
        _Pragma("unroll") for (int j = 0; j < 8; ++j)                                     \
            rf[j] = *(const float4*)(F + (size_t)((mb_) + f_m8 + j) * DIM + d0 + f_dq);   \
        if (tid < 128) {                                                                  \
            _Pragma("unroll") for (int j = 0; j < 8; ++j)                                 \
                q[j] = *(const u16x4*)(Qbf + (size_t)((mb_) + q_m8 + j) * KC + q_kq);     \
        }                                                                                 \
    } while (0)

    LOADCH(m0);
    for (int ch = 0; ch < CH; ++ch) {
        __syncthreads();  // previous chunk's LDS reads done before overwrite
#pragma unroll
        for (int i = 0; i < 4; ++i) {
            int d = f_dq + i;
            uint4 w;
            w.x = (unsigned)(unsigned short)f2bf(rf[0][i]) | ((unsigned)(unsigned short)f2bf(rf[1][i]) << 16);
            w.y = (unsigned)(unsigned short)f2bf(rf[2][i]) | ((unsigned)(unsigned short)f2bf(rf[3][i]) << 16);
            w.z = (unsigned)(unsigned short)f2bf(rf[4][i]) | ((unsigned)(unsigned short)f2bf(rf[5][i]) << 16);
            w.w = (unsigned)(unsigned short)f2bf(rf[6][i]) | ((unsigned)(unsigned short)f2bf(rf[7][i]) << 16);
            int byte = (d * (MB * 2) + f_m8 * 2) ^ ((d & 7) << 4);
            *(uint4*)((char*)ldsF + byte) = w;
        }
        if (tid < 128) {
#pragma unroll
            for (int i = 0; i < 4; ++i) {
                int k = q_kq + i;
                uint4 w;
                w.x = (unsigned)q[0][i] | ((unsigned)q[1][i] << 16);
                w.y = (unsigned)q[2][i] | ((unsigned)q[3][i] << 16);
                w.z = (unsigned)q[4][i] | ((unsigned)q[5][i] << 16);
                w.w = (unsigned)q[6][i] | ((unsigned)q[7][i] << 16);
                int byte = (k * (MB * 2) + q_m8 * 2) ^ ((k & 7) << 4);
                *(uint4*)((char*)ldsQ + byte) = w;
            }
        }
        __syncthreads();
        if (ch + 1 < CH) LOADCH(m0 + (ch + 1) * MB);  // prefetch overlaps MFMA below
#pragma unroll
        for (int h = 0; h < 2; ++h) {
            bf16x8 afr[4];
#pragma unroll
            for (int kt = 0; kt < 4; ++kt) {
                int k = kt * 16 + l15;
                int byte = (k * (MB * 2) + (h * 32 + lhi * 8) * 2) ^ ((k & 7) << 4);
                afr[kt] = *(bf16x8*)((char*)ldsQ + byte);
            }
#pragma unroll
            for (int ds = 0; ds < 2; ++ds) {
                int d = wave * 32 + ds * 16 + l15;
                int byte = (d * (MB * 2) + (h * 32 + lhi * 8) * 2) ^ ((d & 7) << 4);
                bf16x8 bfr = *(bf16x8*)((char*)ldsF + byte);
#pragma unroll
                for (int kt = 0; kt < 4; ++kt)
                    acc[kt][ds] = __builtin_amdgcn_mfma_f32_16x16x32_bf16(afr[kt], bfr, acc[kt][ds], 0, 0, 0);
            }
        }
    }
#undef LOADCH

    float* Pb = P + (size_t)ms * (KC * DIM) + d0;
#pragma unroll
    for (int kt = 0; kt < 4; ++kt)
#pragma unroll
        for (int ds = 0; ds < 2; ++ds) {
            int d = wave * 32 + ds * 16 + l15;
#pragma unroll
            for (int r4 = 0; r4 < 4; ++r4) {
                int k = kt * 16 + lhi * 4 + r4;
                Pb[(size_t)k * DIM + d] = acc[kt][ds][r4];
            }
        }
}

// ---------------- R2: reduce the MSEG partials -> weighted ------------------------
__global__ __launch_bounds__(128) void k_reducep(const float* __restrict__ P,
                                                 float* __restrict__ W) {
    int o = blockIdx.x * 128 + threadIdx.x;  // 0..49151
    const float* p = P + o;
    float s0 = 0.f, s1 = 0.f, s2 = 0.f, s3 = 0.f;
    size_t stride = (size_t)KC * DIM;
#pragma unroll 4
    for (int g = 0; g < MSEG; g += 4) {
        s0 += p[(size_t)g * stride];
        s1 += p[(size_t)(g + 1) * stride];
        s2 += p[(size_t)(g + 2) * stride];
        s3 += p[(size_t)(g + 3) * stride];
    }
    W[o] = (s0 + s1) + (s2 + s3);
}

// ---------------- K4: mass-reduce + finalize centers ------------------------------
__global__ __launch_bounds__(256) void k_final(const float* __restrict__ W,
                                               const float* __restrict__ PSM,
                                               const float* __restrict__ cn,
                                               float* __restrict__ outC) {
    int k = blockIdx.x, tid = threadIdx.x;
    __shared__ float red[4];

    float msum = 0.f;
    for (int p = tid; p < SINK_BLOCKS; p += 256) msum += PSM[(size_t)p * KC + k];
    for (int o = 32; o; o >>= 1) msum += __shfl_xor(msum, o);
    if ((tid & 63) == 0) red[tid >> 6] = msum;
    __syncthreads();
    float mk = fmaxf(red[0] + red[1] + red[2] + red[3], 1e-6f);
    __syncthreads();

    float w[3];
#pragma unroll
    for (int g = 0; g < 3; ++g) w[g] = W[k * DIM + tid + g * 256] / mk;

    float ss = w[0] * w[0] + w[1] * w[1] + w[2] * w[2];
    for (int o = 32; o; o >>= 1) ss += __shfl_xor(ss, o);
    if ((tid & 63) == 0) red[tid >> 6] = ss;
    __syncthreads();
    ss = red[0] + red[1] + red[2] + red[3];
    float n1 = fmaxf(sqrtf(ss), 1e-12f);
    __syncthreads();

    float u0 = 0.99f * cn[k * DIM + tid]       + 0.01f * (w[0] / n1);
    float u1 = 0.99f * cn[k * DIM + tid + 256] + 0.01f * (w[1] / n1);
    float u2 = 0.99f * cn[k * DIM + tid + 512] + 0.01f * (w[2] / n1);
    float ss2 = u0 * u0 + u1 * u1 + u2 * u2;
    for (int o = 32; o; o >>= 1) ss2 += __shfl_xor(ss2, o);
    if ((tid & 63) == 0) red[tid >> 6] = ss2;
    __syncthreads();
    ss2 = red[0] + red[1] + red[2] + red[3];
    float n2 = fmaxf(sqrtf(ss2), 1e-12f);

    outC[k * DIM + tid]       = u0 / n2;
    outC[k * DIM + tid + 256] = u1 / n2;
    outC[k * DIM + tid + 512] = u2 / n2;
}

extern "C" void kernel_launch(void* const* d_in, const int* in_sizes, int n_in,
                              void* d_out, int out_size, void* d_ws, size_t ws_size,
                              hipStream_t stream) {
    const float* F = (const float*)d_in[0];        // [65536][768]
    const float* centers = (const float*)d_in[1];  // [64][768]
    float* out = (float*)d_out;
    float* A = out;                                 // assignments [65536][64]
    float* outC = out + (size_t)M_TOTAL * KC;       // updated centers [64][768]

    float* w = (float*)d_ws;                        // ws = 768 MiB
    float* cn   = w;                                // 49152
    short* cnbf = (short*)(w + 49152);              // 24576 float slots
    float* R0   = w + 73728;                        // 64
    float* R1   = R0 + 64;
    float* R2   = R0 + 128;
    float* invn = w + 73984;                        // 65536
    float* cbuf = w + 139520;                       // 65536
    float* E    = w + 205056;                       // 4194304
    short* Qbf  = (short*)(w + 4399360);            // 2097152 float slots (8 MiB)
    float* PS0  = w + 6496512;                      // 1024*64 (slot sized for 2048*64)
    float* PS1  = w + 6627584;                      // 1024*64 = 65536
    float* PS2  = w + 6693120;                      // 65536
    float* PSM  = w + 6758656;                      // 65536
    float* partial = w + 6824192;                   // MSEG*64*768 = 6291456 (24 MiB)
    float* weighted = w + 13115648;                 // 49152

    k_centers<<<KC, 256, 0, stream>>>(centers, cn, cnbf);
    k_logits<<<LOGITS_BLOCKS, 256, 0, stream>>>(F, cnbf, E, invn, PS0);
    k_redR<0><<<1, 1024, 0, stream>>>(PS0, LOGITS_BLOCKS, nullptr, R0);
    k_sink<0><<<SINK_BLOCKS, 256, 0, stream>>>(E, R0, invn, cbuf, PS1, A, Qbf);
    k_redR<1><<<1, 1024, 0, stream>>>(PS1, SINK_BLOCKS, R0, R1);
    k_sink<1><<<SINK_BLOCKS, 256, 0, stream>>>(E, R1, invn, cbuf, PS2, A, Qbf);
    k_redR<1><<<1, 1024, 0, stream>>>(PS2, SINK_BLOCKS, R1, R2);
    k_sink<2><<<SINK_BLOCKS, 256, 0, stream>>>(E, R2, invn, cbuf, PSM, A, Qbf);

    dim3 wgrid(DIM / DT, MSEG);
    k_weighted<<<wgrid, 256, 0, stream>>>(F, Qbf, partial);
    k_reducep<<<(KC * DIM) / 128, 128, 0, stream>>>(partial, weighted);
    k_final<<<KC, 256, 0, stream>>>(weighted, PSM, cn, outC);
}